// Round 5
// baseline (285.401 us; speedup 1.0000x reference)
//
#include <hip/hip_runtime.h>
#include <hip/hip_bf16.h>

typedef unsigned short u16;
typedef unsigned int u32;
typedef __attribute__((ext_vector_type(8))) short short8;
typedef __attribute__((ext_vector_type(4))) float f32x4;

// aliasing-safe types for type-punned global/LDS access
typedef float __attribute__((may_alias)) f32a;
typedef u32 __attribute__((may_alias)) u32a;
typedef __attribute__((ext_vector_type(2))) float f32x2_t;
typedef f32x2_t __attribute__((may_alias)) f32x2a;
typedef __attribute__((ext_vector_type(4))) float f32x4_t;
typedef f32x4_t __attribute__((may_alias)) f32x4a;
typedef __attribute__((ext_vector_type(2))) u32 u32x2_t;
typedef u32x2_t __attribute__((may_alias)) u32x2a;
typedef short8 __attribute__((may_alias)) short8a;

#define NSLOPE 0.2f
#define BNEPS  1e-5f
#define LOG2E  1.4426950408889634f

union U8 { short8 s; u16 u[8]; u32 w[4]; };

__device__ __forceinline__ u16 f2bf_scalar(float f) {
    union { float f; u32 i; } x; x.f = f;
    u32 u = x.i + 0x7FFFu + ((x.i >> 16) & 1u);
    return (u16)(u >> 16);
}

// packed f32x2 -> bf16x2 (RNE). gfx950 has v_cvt_pk_bf16_f32.
__device__ __forceinline__ u32 cvt2(float a, float b) {
#if __has_builtin(__builtin_amdgcn_cvt_pk_bf16_f32)
    auto p = __builtin_amdgcn_cvt_pk_bf16_f32(a, b);
    u32 w; __builtin_memcpy(&w, &p, sizeof(u32));
    return w;
#else
    return (u32)f2bf_scalar(a) | ((u32)f2bf_scalar(b) << 16);
#endif
}
__device__ __forceinline__ u16 cvt1(float a) { return (u16)cvt2(a, a); }

// lrelu = max(x, 0.2x): 2 VALU ops, exact for all x
__device__ __forceinline__ float lrelu(float x) { return fmaxf(x, NSLOPE * x); }

__device__ __forceinline__ float fexp2(float x) {
#if __has_builtin(__builtin_amdgcn_exp2f)
    return __builtin_amdgcn_exp2f(x);   // v_exp_f32 = 2^x
#else
    return exp2f(x);
#endif
}

__device__ __forceinline__ float frcp(float x) {
#if __has_builtin(__builtin_amdgcn_rcpf)
    return __builtin_amdgcn_rcpf(x);    // v_rcp_f32, ~1ulp — fine at this tolerance
#else
    return 1.f / x;
#endif
}

__device__ __forceinline__ float ldf(const void* p, size_t i) { return ((const f32a*)p)[i]; }

// B-fragment for mfma_f32_16x16x32_bf16 from fp32 global W, BN scale folded in:
// lane holds B[k = ks*32 + q*8 + j][n = nt*16 + t] * scale   (epilogue only)
__device__ __forceinline__ short8 load_bfrag(const void* W, int K, int Cn, int ks, int nt,
                                             int q, int t, float scale) {
    U8 x;
#pragma unroll
    for (int j = 0; j < 8; ++j) {
        int k = ks * 32 + q * 8 + j;
        x.u[j] = (k < K) ? f2bf_scalar(ldf(W, (size_t)k * Cn + nt * 16 + t) * scale) : (u16)0;
    }
    return x.s;
}

// A-fragment from per-wave LDS tile row-major [16][68] bf16 — two b64 reads
// (byte addr row*136 + ks*64 + q*16: 8B-aligned). Same-wave DS is in-order.
__device__ __forceinline__ short8 lds_afrag(const u16* buf, int row, int ks, int q) {
    const u16* cp = buf + row * 68 + ks * 32 + q * 8;
    u32x2a a = *(const u32x2a*)cp;
    u32x2a b = *(const u32x2a*)(cp + 4);
    U8 x; x.w[0] = a.x; x.w[1] = a.y; x.w[2] = b.x; x.w[3] = b.y;
    return x.s;
}

// B-fragment from a per-lane weight base (s_w*T + t*64 + swizzled slot for this ks,q):
// one ds_read_b128 at imm offset nt*2048B. XOR slot swizzle keeps a q-group's 16
// lanes spread over all 8 16B slots (2 lanes/bank at the b128 floor = free).
__device__ __forceinline__ short8 lds_wfrag2(const u16* base, int nt) {
    return *(const short8a*)(base + (nt << 10));
}

#define MFMA(a, b, c) __builtin_amdgcn_mfma_f32_16x16x32_bf16((a), (b), (c), 0, 0, 0)

// One wave = one group of 16 points. cat/h/pool tiles are PER-WAVE: no in-loop barriers.
// R11: R4 showed the unified budget splits 64 VGPR + 64 AGPR under waves_per_eu(4,4);
// peak live ~145 > 128 -> 17-dword scratch (WRITE 69.6MB vs 33.5 ideal). Fix both ends:
// (a) amdgpu_waves_per_eu(3,4): hard budget 168 (R0's proven no-spill regime), allocator
//     aspiration capped at 4 waves/EU; (b) prefetch loads issued MID-BODY (after raw-MLP)
//     so the 24 f32 prefetch regs overlap only phases B/C, cutting peak live to ~115.
// Anti-LICM 'licm' keeps weight ds_reads in-loop (R1 lesson: LICM rehoists them into
// 64 regs otherwise). Slot-permuted packed LDS writes, select-then-rcp softmax,
// cndmask load_raw, bias-in-row-10 carried from R3/R4.
__global__
__attribute__((amdgpu_flat_work_group_size(256, 256), amdgpu_waves_per_eu(3, 4)))
void lfa_kernel(
    const void* __restrict__ feat,        // (131072, 32) fp32
    const void* __restrict__ rawf,        // (131072*16, 10) fp32
    const int*  __restrict__ nbidx,       // (131072, 16) int32
    const void* __restrict__ w_raw,
    const void* __restrict__ b_raw, const void* __restrict__ g_raw,
    const void* __restrict__ be_raw, const void* __restrict__ m_raw,
    const void* __restrict__ v_raw,
    const void* __restrict__ w_nb,
    const void* __restrict__ b_nb, const void* __restrict__ g_nb,
    const void* __restrict__ be_nb, const void* __restrict__ m_nb,
    const void* __restrict__ v_nb,
    const void* __restrict__ w_attn,
    const void* __restrict__ w_out,
    const void* __restrict__ b_out, const void* __restrict__ g_out,
    const void* __restrict__ be_out, const void* __restrict__ m_out,
    const void* __restrict__ v_out,
    const void* __restrict__ w_sc,
    const void* __restrict__ b_sc, const void* __restrict__ g_sc,
    const void* __restrict__ be_sc, const void* __restrict__ m_sc,
    const void* __restrict__ v_sc,
    float* __restrict__ outp)             // (131072, 64) fp32
{
    // h tile aliases the cat tile: every iteration fully rewrites cat[0..15][0..63]
    // before phase B reads it, and same-wave DS ops execute in order.
    //
    // K-slot <-> channel permutation (so MFMA outputs pack into contiguous LDS slots):
    //   cat slots  0..31 : gather channel s (identity)
    //   cat slots 32..63 : raw-MLP channel ((s-32)&1)*16 + ((s-32)>>1)   [slot 32+2t+nt]
    //   h   slots  0..63 : h channel (s&3)*16 + (s>>2)                   [slot 4t+nt]
    // s_wnbT rows use the cat permutation; s_wattT rows use the h permutation.
    __shared__ __align__(16) u16 s_cat[4][16 * 68];
    __shared__ __align__(16) u16 s_pool[4][16 * 68];
    __shared__ __align__(16) u16 s_wnbT[64 * 64];    // W_nb^T * s_nb, bf16, swizzled
    __shared__ __align__(16) u16 s_wattT[64 * 64];   // W_attn^T * log2e, bf16, swizzled
    __shared__ float2 s_pr_raw[32];
    __shared__ float2 s_pr_nb[64];
    __shared__ float2 s_pr_out[64];
    __shared__ float2 s_pr_sc[64];

    const int tid  = threadIdx.x;
    const int lane = tid & 63;
    const int wv   = tid >> 6;
    const int t    = lane & 15;
    const int q    = lane >> 4;

    // ---- fold BN (+linear bias) into per-channel scale/bias ----
    if (tid < 64) {
        int c = tid;
        float s = ldf(g_nb, c) * rsqrtf(ldf(v_nb, c) + BNEPS);
        s_pr_nb[c] = make_float2(s, (ldf(b_nb, c) - ldf(m_nb, c)) * s + ldf(be_nb, c));
    } else if (tid < 128) {
        int c = tid - 64;
        float s = ldf(g_out, c) * rsqrtf(ldf(v_out, c) + BNEPS);
        s_pr_out[c] = make_float2(s, (ldf(b_out, c) - ldf(m_out, c)) * s + ldf(be_out, c));
    } else if (tid < 192) {
        int c = tid - 128;
        float s = ldf(g_sc, c) * rsqrtf(ldf(v_sc, c) + BNEPS);
        s_pr_sc[c] = make_float2(s, (ldf(b_sc, c) - ldf(m_sc, c)) * s + ldf(be_sc, c));
    } else if (tid < 224) {
        int c = tid - 192;
        float s = ldf(g_raw, c) * rsqrtf(ldf(v_raw, c) + BNEPS);
        s_pr_raw[c] = make_float2(s, (ldf(b_raw, c) - ldf(m_raw, c)) * s + ldf(be_raw, c));
    }
    __syncthreads();

    // ---- cooperative fill of the shared bf16 weight images (coalesced: n fast) ----
#pragma unroll 4
    for (int idx = tid; idx < 64 * 64; idx += 256) {
        int n = idx & 63, s = idx >> 6;    // s = K-slot
        int off = (n << 6) | (((s >> 3) ^ (n & 7)) << 3) | (s & 7);
        int knb = (s < 32) ? s : 32 + (((s - 32) & 1) << 4) + ((s - 32) >> 1);
        int kat = ((s & 3) << 4) + (s >> 2);
        s_wnbT[off]  = f2bf_scalar(ldf(w_nb,   (size_t)knb * 64 + n) * s_pr_nb[n].x);
        s_wattT[off] = f2bf_scalar(ldf(w_attn, (size_t)kat * 64 + n) * LOG2E);
    }
    __syncthreads();   // last block-wide barrier

    // ---- small loop-resident state: raw weights (scale folded; BN bias in row 10) ----
    short8 wraw[2];
    float bias_nb[4];
#pragma unroll
    for (int nt = 0; nt < 2; ++nt) {
        int c = nt * 16 + t;
        float2 pr = s_pr_raw[c];
        U8 x;
#pragma unroll
        for (int j = 0; j < 8; ++j) {
            int k = q * 8 + j;
            float v = (k < 10) ? ldf(w_raw, (size_t)k * 32 + c) * pr.x
                               : (k == 10 ? pr.y : 0.f);
            x.u[j] = f2bf_scalar(v);
        }
        wraw[nt] = x.s;
    }
#pragma unroll
    for (int nt = 0; nt < 4; ++nt) bias_nb[nt] = s_pr_nb[nt * 16 + t].y;

    // per-lane swizzled weight bases (iter-invariant; frag read = base + nt*2048B imm)
    const u16* wnb_base[2];
    const u16* watt_base[2];
#pragma unroll
    for (int ks = 0; ks < 2; ++ks) {
        int lane_off = (t << 6) + ((((ks << 2) | q) ^ (t & 7)) << 3);
        wnb_base[ks]  = s_wnbT  + lane_off;
        watt_base[ks] = s_wattT + lane_off;
    }

    u16* catw  = &s_cat[wv][0];
    u16* poolw = &s_pool[wv][0];

    const f32x4 zf = {0.f, 0.f, 0.f, 0.f};
    const int g  = blockIdx.x * 4 + wv;     // 8192 groups, grid 2048 x 4 waves
    const int P0 = g * 16;
    const int bb = P0 >> 16;                // group never straddles batch boundary
    const size_t fb = (size_t)bb << 16;

    const int m_ = lane >> 2;               // gather: neighbor index this lane handles
    const int pc = lane & 3;                // gather: 8-float piece

    // hoisted per-wave base pointers
    const int*  nbp  = nbidx + P0 * 16 + m_;                       // idx for point p: nbp[p*16]
    const f32a* rawp = (const f32a*)rawf + (size_t)P0 * 160 + (size_t)t * 10;  // + p*160
    const float* fpb = (const float*)feat;

    // lane-invariant select masks (hoisted into SGPR pairs by LICM)
    const bool q_lt2 = (q < 2), q_eq0 = (q == 0), q_eq1 = (q == 1);

    // branch-free loaders -> SSA f32x4 pairs (no structs: avoid private-stack demotion)
    auto load_gather = [&](int ix, f32x4& a, f32x4& b) {
        const float* fp = fpb + (fb + (size_t)ix) * 32 + pc * 8;
        a = *(const f32x4a*)fp;
        b = *(const f32x4a*)(fp + 4);
    };
    // lane(t,q) supplies raw[t][k], k=q*8+j; rows are 10 floats. q0 reads f0..7,
    // q1 reads f8..9 (same b64 slot via +8 offset), bias 1.0 rides k=10; q>=2 zeros.
    auto load_raw = [&](int p, f32x4& a, f32x4& b) {
        const f32a* rp = rawp + (size_t)p * 160;
        f32x2a L0 = *(const f32x2a*)(rp + ((q & 1) << 3));  // q0:f01  q1:f89 (q2/q3 masked)
        f32x2a L1 = *(const f32x2a*)(rp + 2);
        f32x2a L2 = *(const f32x2a*)(rp + 4);
        f32x2a L3 = *(const f32x2a*)(rp + 6);
        a.x = q_lt2 ? L0.x : 0.f;
        a.y = q_lt2 ? L0.y : 0.f;
        a.z = q_eq0 ? L1.x : (q_eq1 ? 1.f : 0.f);
        a.w = q_eq0 ? L1.y : 0.f;
        b.x = q_eq0 ? L2.x : 0.f;  b.y = q_eq0 ? L2.y : 0.f;
        b.z = q_eq0 ? L3.x : 0.f;  b.w = q_eq0 ? L3.y : 0.f;
    };

    // ---- software-pipeline preamble: loop-carried state is PACKED bf16 (8 u32) ----
    u32x2_t gpa, gpb;       // gather row, bf16x2 packed (lo 4, hi 4)
    u32 rp0, rp1, rp2, rp3; // raw-MLP A fragment, packed
    {
        int ixA = nbp[0];
        f32x4 g0, g1, r0, r1;
        load_gather(ixA, g0, g1);
        load_raw(0, r0, r1);
        gpa.x = cvt2(g0.x, g0.y); gpa.y = cvt2(g0.z, g0.w);
        gpb.x = cvt2(g1.x, g1.y); gpb.y = cvt2(g1.z, g1.w);
        rp0 = cvt2(r0.x, r0.y); rp1 = cvt2(r0.z, r0.w);
        rp2 = cvt2(r1.x, r1.y); rp3 = cvt2(r1.z, r1.w);
    }
    int ixB = nbp[16];
    int licm = 0;   // always 0; opaque to the compiler (anti-LICM for weight reads)

#pragma unroll 1
    for (int p = 0; p < 16; ++p) {
        asm volatile("" : "+v"(licm));

        // next-next neighbor index (1 reg, cheap; full-body latency cover)
        const int pnn = (p + 2 < 16) ? p + 2 : 15;
        int ixC = nbp[pnn * 16];

        // ---- phase A: gather -> cat[m][0..31] (carried packed, b64 LDS writes) ----
        *(u32x2a*)(catw + m_ * 68 + pc * 8)     = gpa;
        *(u32x2a*)(catw + m_ * 68 + pc * 8 + 4) = gpb;

        // ---- raw MLP via MFMA (bias in row 10) -> cat slots 32+2t+nt (packed b32) ----
        {
            U8 au;
            au.w[0] = rp0; au.w[1] = rp1; au.w[2] = rp2; au.w[3] = rp3;
            short8 ar = au.s;
            f32x4 racc0 = MFMA(ar, wraw[0], zf);
            f32x4 racc1 = MFMA(ar, wraw[1], zf);
#pragma unroll
            for (int r = 0; r < 4; ++r) {
                u32 wpk = cvt2(lrelu(racc0[r]), lrelu(racc1[r]));
                *(u32a*)(catw + (q * 4 + r) * 68 + 32 + 2 * t) = wpk;
            }
        }

        // ---- MID-BODY prefetch issue: carried regs now dead; loads cover phases B+C.
        // (Issuing here instead of at the top halves the 24-f32 live range — the
        //  register-pressure fix that keeps peak live under the allocator budget.)
        const int pn = (p + 1 < 16) ? p + 1 : 15;
        f32x4 gb0, gb1, rb0, rb1;
        load_gather(ixB, gb0, gb1);
        load_raw(pn, rb0, rb1);

        // ---- phase B: h = lrelu(cat @ (w_nb*s) + bias); packed b64 h writes ----
        short8 a0 = lds_afrag(catw, t, 0, q);
        short8 a1 = lds_afrag(catw, t, 1, q);
        const u16* wb0 = wnb_base[0] + licm;
        const u16* wb1 = wnb_base[1] + licm;
        float hv[4][4];
#pragma unroll
        for (int nt = 0; nt < 4; ++nt) {
            f32x4 a = MFMA(a0, lds_wfrag2(wb0, nt), zf);
            a = MFMA(a1, lds_wfrag2(wb1, nt), a);
#pragma unroll
            for (int r = 0; r < 4; ++r) hv[nt][r] = lrelu(a[r] + bias_nb[nt]);
        }
#pragma unroll
        for (int r = 0; r < 4; ++r) {
            u32x2_t w2;
            w2.x = cvt2(hv[0][r], hv[1][r]);
            w2.y = cvt2(hv[2][r], hv[3][r]);
            *(u32x2a*)(catw + (q * 4 + r) * 68 + 4 * t) = w2;   // h slot 4t+nt
        }

        // ---- phase C: scores = h @ (w_attn*log2e); softmax over m via exp2; pool ----
        short8 h0 = lds_afrag(catw, t, 0, q);
        short8 h1 = lds_afrag(catw, t, 1, q);
        const u16* wa0 = watt_base[0] + licm;
        const u16* wa1 = watt_base[1] + licm;
        float pvn = 0.f, pvd = 1.f;
#pragma unroll
        for (int nt = 0; nt < 4; ++nt) {
            f32x4 s = MFMA(h0, lds_wfrag2(wa0, nt), zf);
            s = MFMA(h1, lds_wfrag2(wa1, nt), s);
            float num = 0.f, den = 0.f;
#pragma unroll
            for (int r = 0; r < 4; ++r) {
                float e = fexp2(s[r]);      // no max-sub: |score*log2e| << 126
                num += e * hv[nt][r];
                den += e;
            }
            num += __shfl_xor(num, 16); den += __shfl_xor(den, 16);
            num += __shfl_xor(num, 32); den += __shfl_xor(den, 32);
            // lane only consumes its own q's channel group: select, divide once later
            bool sel = (q == nt);
            pvn = sel ? num : pvn;
            pvd = sel ? den : pvd;
        }
        poolw[p * 68 + q * 16 + t] = cvt1(pvn * frcp(pvd));

        // ---- bottom: convert this iteration's prefetch into the packed carry ----
        gpa.x = cvt2(gb0.x, gb0.y); gpa.y = cvt2(gb0.z, gb0.w);
        gpb.x = cvt2(gb1.x, gb1.y); gpb.y = cvt2(gb1.z, gb1.w);
        rp0 = cvt2(rb0.x, rb0.y); rp1 = cvt2(rb0.z, rb0.w);
        rp2 = cvt2(rb1.x, rb1.y); rp3 = cvt2(rb1.z, rb1.w);
        ixB = ixC;
    }

    // ---- epilogue: out = pooled @ (w_out*s) ; sc = bn(feat @ (w_sc*s)); lrelu(sum+bias) ----
    short8 wout[2][4], wsc[4];
    float bias_os[4];
#pragma unroll
    for (int nt = 0; nt < 4; ++nt) {
        float2 po = s_pr_out[nt * 16 + t];
        float2 ps = s_pr_sc[nt * 16 + t];
        bias_os[nt] = po.y + ps.y;
#pragma unroll
        for (int ks = 0; ks < 2; ++ks)
            wout[ks][nt] = load_bfrag(w_out, 64, 64, ks, nt, q, t, po.x);
        wsc[nt] = load_bfrag(w_sc, 32, 64, 0, nt, q, t, ps.x);
    }

    short8 pf0 = lds_afrag(poolw, t, 0, q);
    short8 pf1 = lds_afrag(poolw, t, 1, q);
    U8 sxu;
    {
        const float* fp = fpb + (size_t)(P0 + t) * 32 + q * 8;
        f32x4a v0 = *(const f32x4a*)fp;
        f32x4a v1 = *(const f32x4a*)(fp + 4);
        sxu.w[0] = cvt2(v0.x, v0.y); sxu.w[1] = cvt2(v0.z, v0.w);
        sxu.w[2] = cvt2(v1.x, v1.y); sxu.w[3] = cvt2(v1.z, v1.w);
    }
    short8 scf = sxu.s;
#pragma unroll
    for (int nt = 0; nt < 4; ++nt) {
        f32x4 oa = {bias_os[nt], bias_os[nt], bias_os[nt], bias_os[nt]};
        oa = MFMA(pf0, wout[0][nt], oa);
        oa = MFMA(pf1, wout[1][nt], oa);
        f32x4 sa = MFMA(scf, wsc[nt], zf);
#pragma unroll
        for (int r = 0; r < 4; ++r)
            outp[(size_t)(P0 + q * 4 + r) * 64 + nt * 16 + t] = lrelu(oa[r] + sa[r]);
    }
}

extern "C" void kernel_launch(void* const* d_in, const int* in_sizes, int n_in,
                              void* d_out, int out_size, void* d_ws, size_t ws_size,
                              hipStream_t stream) {
    hipLaunchKernelGGL(lfa_kernel, dim3(2048), dim3(256), 0, stream,
                       d_in[0], d_in[1], (const int*)d_in[2],
                       d_in[3], d_in[4], d_in[5], d_in[6], d_in[7], d_in[8],
                       d_in[9], d_in[10], d_in[11], d_in[12], d_in[13], d_in[14],
                       d_in[15],
                       d_in[16], d_in[17], d_in[18], d_in[19], d_in[20], d_in[21],
                       d_in[22], d_in[23], d_in[24], d_in[25], d_in[26], d_in[27],
                       (float*)d_out);
}

// Round 6
// 281.257 us; speedup vs baseline: 1.0147x; 1.0147x over previous
//
#include <hip/hip_runtime.h>
#include <hip/hip_bf16.h>

typedef unsigned short u16;
typedef unsigned int u32;
typedef __attribute__((ext_vector_type(8))) short short8;
typedef __attribute__((ext_vector_type(4))) float f32x4;

// aliasing-safe types for type-punned global/LDS access
typedef float __attribute__((may_alias)) f32a;
typedef u32 __attribute__((may_alias)) u32a;
typedef __attribute__((ext_vector_type(2))) float f32x2_t;
typedef f32x2_t __attribute__((may_alias)) f32x2a;
typedef __attribute__((ext_vector_type(4))) float f32x4_t;
typedef f32x4_t __attribute__((may_alias)) f32x4a;
typedef __attribute__((ext_vector_type(2))) u32 u32x2_t;
typedef u32x2_t __attribute__((may_alias)) u32x2a;
typedef short8 __attribute__((may_alias)) short8a;

#define NSLOPE 0.2f
#define BNEPS  1e-5f
#define LOG2E  1.4426950408889634f

union U8 { short8 s; u16 u[8]; u32 w[4]; };

__device__ __forceinline__ u16 f2bf_scalar(float f) {
    union { float f; u32 i; } x; x.f = f;
    u32 u = x.i + 0x7FFFu + ((x.i >> 16) & 1u);
    return (u16)(u >> 16);
}

// packed f32x2 -> bf16x2 (RNE). gfx950 has v_cvt_pk_bf16_f32.
__device__ __forceinline__ u32 cvt2(float a, float b) {
#if __has_builtin(__builtin_amdgcn_cvt_pk_bf16_f32)
    auto p = __builtin_amdgcn_cvt_pk_bf16_f32(a, b);
    u32 w; __builtin_memcpy(&w, &p, sizeof(u32));
    return w;
#else
    return (u32)f2bf_scalar(a) | ((u32)f2bf_scalar(b) << 16);
#endif
}
__device__ __forceinline__ u16 cvt1(float a) { return (u16)cvt2(a, a); }

// lrelu = max(x, 0.2x): 2 VALU ops, exact for all x
__device__ __forceinline__ float lrelu(float x) { return fmaxf(x, NSLOPE * x); }

__device__ __forceinline__ float fexp2(float x) {
#if __has_builtin(__builtin_amdgcn_exp2f)
    return __builtin_amdgcn_exp2f(x);   // v_exp_f32 = 2^x
#else
    return exp2f(x);
#endif
}

__device__ __forceinline__ float frcp(float x) {
#if __has_builtin(__builtin_amdgcn_rcpf)
    return __builtin_amdgcn_rcpf(x);    // v_rcp_f32, ~1ulp — fine at this tolerance
#else
    return 1.f / x;
#endif
}

__device__ __forceinline__ float bits2f(u32 b) {
    union { u32 u; float f; } x; x.u = b; return x.f;
}

__device__ __forceinline__ float ldf(const void* p, size_t i) { return ((const f32a*)p)[i]; }

// B-fragment for mfma_f32_16x16x32_bf16 from fp32 global W, BN scale folded in:
// lane holds B[k = ks*32 + q*8 + j][n = nt*16 + t] * scale   (epilogue only)
__device__ __forceinline__ short8 load_bfrag(const void* W, int K, int Cn, int ks, int nt,
                                             int q, int t, float scale) {
    U8 x;
#pragma unroll
    for (int j = 0; j < 8; ++j) {
        int k = ks * 32 + q * 8 + j;
        x.u[j] = (k < K) ? f2bf_scalar(ldf(W, (size_t)k * Cn + nt * 16 + t) * scale) : (u16)0;
    }
    return x.s;
}

// A-fragment from per-wave LDS tile row-major [16][68] bf16 — two b64 reads
// (byte addr row*136 + ks*64 + q*16: 8B-aligned). Same-wave DS is in-order.
__device__ __forceinline__ short8 lds_afrag(const u16* buf, int row, int ks, int q) {
    const u16* cp = buf + row * 68 + ks * 32 + q * 8;
    u32x2a a = *(const u32x2a*)cp;
    u32x2a b = *(const u32x2a*)(cp + 4);
    U8 x; x.w[0] = a.x; x.w[1] = a.y; x.w[2] = b.x; x.w[3] = b.y;
    return x.s;
}

// B-fragment from a per-lane weight base (s_w*T + t*64 + swizzled slot for this ks,q):
// one ds_read_b128 at imm offset nt*2048B. XOR slot swizzle keeps a q-group's 16
// lanes spread over all 8 16B slots (2 lanes/bank at the b128 floor = free).
__device__ __forceinline__ short8 lds_wfrag2(const u16* base, int nt) {
    return *(const short8a*)(base + (nt << 10));
}

#define MFMA(a, b, c) __builtin_amdgcn_mfma_f32_16x16x32_bf16((a), (b), (c), 0, 0, 0)

// One wave = one group of 16 points. cat/h/pool tiles are PER-WAVE: no in-loop barriers.
// R12: R5 found the ALLOCATION DRIVER was the epilogue (12 resident short8 frags = 96
// regs + pf/scf ~ 130 peak) — that's what spilled at every 128-reg budget (R4's 36MB
// WRITE excess = 2048*256*17dw exactly). Fixes: (a) epilogue fused per-nt (peak ~70);
// (b) h kept as the packed bf16 pairs hp[4] we already cvt2 for the LDS write (loop
// peak -8; phase C unpacks at 1 VALU/use); (c) retry waves_per_eu(4,4) -> 4 blocks/CU.
// Anti-LICM 'licm' keeps weight ds_reads in-loop (R1: LICM rehoists them into 64 regs).
// Mid-body prefetch, slot-permuted packed LDS writes, select-then-rcp softmax,
// cndmask load_raw, bias-in-row-10 carried from R3-R5.
__global__
__attribute__((amdgpu_flat_work_group_size(256, 256), amdgpu_waves_per_eu(4, 4)))
void lfa_kernel(
    const void* __restrict__ feat,        // (131072, 32) fp32
    const void* __restrict__ rawf,        // (131072*16, 10) fp32
    const int*  __restrict__ nbidx,       // (131072, 16) int32
    const void* __restrict__ w_raw,
    const void* __restrict__ b_raw, const void* __restrict__ g_raw,
    const void* __restrict__ be_raw, const void* __restrict__ m_raw,
    const void* __restrict__ v_raw,
    const void* __restrict__ w_nb,
    const void* __restrict__ b_nb, const void* __restrict__ g_nb,
    const void* __restrict__ be_nb, const void* __restrict__ m_nb,
    const void* __restrict__ v_nb,
    const void* __restrict__ w_attn,
    const void* __restrict__ w_out,
    const void* __restrict__ b_out, const void* __restrict__ g_out,
    const void* __restrict__ be_out, const void* __restrict__ m_out,
    const void* __restrict__ v_out,
    const void* __restrict__ w_sc,
    const void* __restrict__ b_sc, const void* __restrict__ g_sc,
    const void* __restrict__ be_sc, const void* __restrict__ m_sc,
    const void* __restrict__ v_sc,
    float* __restrict__ outp)             // (131072, 64) fp32
{
    // h tile aliases the cat tile: every iteration fully rewrites cat[0..15][0..63]
    // before phase B reads it, and same-wave DS ops execute in order.
    //
    // K-slot <-> channel permutation (so MFMA outputs pack into contiguous LDS slots):
    //   cat slots  0..31 : gather channel s (identity)
    //   cat slots 32..63 : raw-MLP channel ((s-32)&1)*16 + ((s-32)>>1)   [slot 32+2t+nt]
    //   h   slots  0..63 : h channel (s&3)*16 + (s>>2)                   [slot 4t+nt]
    // s_wnbT rows use the cat permutation; s_wattT rows use the h permutation.
    __shared__ __align__(16) u16 s_cat[4][16 * 68];
    __shared__ __align__(16) u16 s_pool[4][16 * 68];
    __shared__ __align__(16) u16 s_wnbT[64 * 64];    // W_nb^T * s_nb, bf16, swizzled
    __shared__ __align__(16) u16 s_wattT[64 * 64];   // W_attn^T * log2e, bf16, swizzled
    __shared__ float2 s_pr_raw[32];
    __shared__ float2 s_pr_nb[64];
    __shared__ float2 s_pr_out[64];
    __shared__ float2 s_pr_sc[64];

    const int tid  = threadIdx.x;
    const int lane = tid & 63;
    const int wv   = tid >> 6;
    const int t    = lane & 15;
    const int q    = lane >> 4;

    // ---- fold BN (+linear bias) into per-channel scale/bias ----
    if (tid < 64) {
        int c = tid;
        float s = ldf(g_nb, c) * rsqrtf(ldf(v_nb, c) + BNEPS);
        s_pr_nb[c] = make_float2(s, (ldf(b_nb, c) - ldf(m_nb, c)) * s + ldf(be_nb, c));
    } else if (tid < 128) {
        int c = tid - 64;
        float s = ldf(g_out, c) * rsqrtf(ldf(v_out, c) + BNEPS);
        s_pr_out[c] = make_float2(s, (ldf(b_out, c) - ldf(m_out, c)) * s + ldf(be_out, c));
    } else if (tid < 192) {
        int c = tid - 128;
        float s = ldf(g_sc, c) * rsqrtf(ldf(v_sc, c) + BNEPS);
        s_pr_sc[c] = make_float2(s, (ldf(b_sc, c) - ldf(m_sc, c)) * s + ldf(be_sc, c));
    } else if (tid < 224) {
        int c = tid - 192;
        float s = ldf(g_raw, c) * rsqrtf(ldf(v_raw, c) + BNEPS);
        s_pr_raw[c] = make_float2(s, (ldf(b_raw, c) - ldf(m_raw, c)) * s + ldf(be_raw, c));
    }
    __syncthreads();

    // ---- cooperative fill of the shared bf16 weight images (coalesced: n fast) ----
#pragma unroll 4
    for (int idx = tid; idx < 64 * 64; idx += 256) {
        int n = idx & 63, s = idx >> 6;    // s = K-slot
        int off = (n << 6) | (((s >> 3) ^ (n & 7)) << 3) | (s & 7);
        int knb = (s < 32) ? s : 32 + (((s - 32) & 1) << 4) + ((s - 32) >> 1);
        int kat = ((s & 3) << 4) + (s >> 2);
        s_wnbT[off]  = f2bf_scalar(ldf(w_nb,   (size_t)knb * 64 + n) * s_pr_nb[n].x);
        s_wattT[off] = f2bf_scalar(ldf(w_attn, (size_t)kat * 64 + n) * LOG2E);
    }
    __syncthreads();   // last block-wide barrier

    // ---- small loop-resident state: raw weights (scale folded; BN bias in row 10) ----
    short8 wraw[2];
    float bias_nb[4];
#pragma unroll
    for (int nt = 0; nt < 2; ++nt) {
        int c = nt * 16 + t;
        float2 pr = s_pr_raw[c];
        U8 x;
#pragma unroll
        for (int j = 0; j < 8; ++j) {
            int k = q * 8 + j;
            float v = (k < 10) ? ldf(w_raw, (size_t)k * 32 + c) * pr.x
                               : (k == 10 ? pr.y : 0.f);
            x.u[j] = f2bf_scalar(v);
        }
        wraw[nt] = x.s;
    }
#pragma unroll
    for (int nt = 0; nt < 4; ++nt) bias_nb[nt] = s_pr_nb[nt * 16 + t].y;

    // per-lane swizzled weight bases (iter-invariant; frag read = base + nt*2048B imm)
    const u16* wnb_base[2];
    const u16* watt_base[2];
#pragma unroll
    for (int ks = 0; ks < 2; ++ks) {
        int lane_off = (t << 6) + ((((ks << 2) | q) ^ (t & 7)) << 3);
        wnb_base[ks]  = s_wnbT  + lane_off;
        watt_base[ks] = s_wattT + lane_off;
    }

    u16* catw  = &s_cat[wv][0];
    u16* poolw = &s_pool[wv][0];

    const f32x4 zf = {0.f, 0.f, 0.f, 0.f};
    const int g  = blockIdx.x * 4 + wv;     // 8192 groups, grid 2048 x 4 waves
    const int P0 = g * 16;
    const int bb = P0 >> 16;                // group never straddles batch boundary
    const size_t fb = (size_t)bb << 16;

    const int m_ = lane >> 2;               // gather: neighbor index this lane handles
    const int pc = lane & 3;                // gather: 8-float piece

    // hoisted per-wave base pointers
    const int*  nbp  = nbidx + P0 * 16 + m_;                       // idx for point p: nbp[p*16]
    const f32a* rawp = (const f32a*)rawf + (size_t)P0 * 160 + (size_t)t * 10;  // + p*160
    const float* fpb = (const float*)feat;

    // lane-invariant select masks (hoisted into SGPR pairs by LICM)
    const bool q_lt2 = (q < 2), q_eq0 = (q == 0), q_eq1 = (q == 1);

    // branch-free loaders -> SSA f32x4 pairs (no structs: avoid private-stack demotion)
    auto load_gather = [&](int ix, f32x4& a, f32x4& b) {
        const float* fp = fpb + (fb + (size_t)ix) * 32 + pc * 8;
        a = *(const f32x4a*)fp;
        b = *(const f32x4a*)(fp + 4);
    };
    // lane(t,q) supplies raw[t][k], k=q*8+j; rows are 10 floats. q0 reads f0..7,
    // q1 reads f8..9 (same b64 slot via +8 offset), bias 1.0 rides k=10; q>=2 zeros.
    auto load_raw = [&](int p, f32x4& a, f32x4& b) {
        const f32a* rp = rawp + (size_t)p * 160;
        f32x2a L0 = *(const f32x2a*)(rp + ((q & 1) << 3));  // q0:f01  q1:f89 (q2/q3 masked)
        f32x2a L1 = *(const f32x2a*)(rp + 2);
        f32x2a L2 = *(const f32x2a*)(rp + 4);
        f32x2a L3 = *(const f32x2a*)(rp + 6);
        a.x = q_lt2 ? L0.x : 0.f;
        a.y = q_lt2 ? L0.y : 0.f;
        a.z = q_eq0 ? L1.x : (q_eq1 ? 1.f : 0.f);
        a.w = q_eq0 ? L1.y : 0.f;
        b.x = q_eq0 ? L2.x : 0.f;  b.y = q_eq0 ? L2.y : 0.f;
        b.z = q_eq0 ? L3.x : 0.f;  b.w = q_eq0 ? L3.y : 0.f;
    };

    // ---- software-pipeline preamble: loop-carried state is PACKED bf16 (8 u32) ----
    u32x2_t gpa, gpb;       // gather row, bf16x2 packed (lo 4, hi 4)
    u32 rp0, rp1, rp2, rp3; // raw-MLP A fragment, packed
    {
        int ixA = nbp[0];
        f32x4 g0, g1, r0, r1;
        load_gather(ixA, g0, g1);
        load_raw(0, r0, r1);
        gpa.x = cvt2(g0.x, g0.y); gpa.y = cvt2(g0.z, g0.w);
        gpb.x = cvt2(g1.x, g1.y); gpb.y = cvt2(g1.z, g1.w);
        rp0 = cvt2(r0.x, r0.y); rp1 = cvt2(r0.z, r0.w);
        rp2 = cvt2(r1.x, r1.y); rp3 = cvt2(r1.z, r1.w);
    }
    int ixB = nbp[16];
    int licm = 0;   // always 0; opaque to the compiler (anti-LICM for weight reads)

#pragma unroll 1
    for (int p = 0; p < 16; ++p) {
        asm volatile("" : "+v"(licm));

        // next-next neighbor index (1 reg, cheap; full-body latency cover)
        const int pnn = (p + 2 < 16) ? p + 2 : 15;
        int ixC = nbp[pnn * 16];

        // ---- phase A: gather -> cat[m][0..31] (carried packed, b64 LDS writes) ----
        *(u32x2a*)(catw + m_ * 68 + pc * 8)     = gpa;
        *(u32x2a*)(catw + m_ * 68 + pc * 8 + 4) = gpb;

        // ---- raw MLP via MFMA (bias in row 10) -> cat slots 32+2t+nt (packed b32) ----
        {
            U8 au;
            au.w[0] = rp0; au.w[1] = rp1; au.w[2] = rp2; au.w[3] = rp3;
            short8 ar = au.s;
            f32x4 racc0 = MFMA(ar, wraw[0], zf);
            f32x4 racc1 = MFMA(ar, wraw[1], zf);
#pragma unroll
            for (int r = 0; r < 4; ++r) {
                u32 wpk = cvt2(lrelu(racc0[r]), lrelu(racc1[r]));
                *(u32a*)(catw + (q * 4 + r) * 68 + 32 + 2 * t) = wpk;
            }
        }

        // ---- MID-BODY prefetch issue: carried regs now dead; loads cover phases B+C ----
        const int pn = (p + 1 < 16) ? p + 1 : 15;
        f32x4 gb0, gb1, rb0, rb1;
        load_gather(ixB, gb0, gb1);
        load_raw(pn, rb0, rb1);

        // ---- phase B: h = lrelu(cat @ (w_nb*s) + bias); h kept PACKED (hp = the
        //      exact words written to LDS; phase C unpacks at 1 VALU per use) ----
        short8 a0 = lds_afrag(catw, t, 0, q);
        short8 a1 = lds_afrag(catw, t, 1, q);
        const u16* wb0 = wnb_base[0] + licm;
        const u16* wb1 = wnb_base[1] + licm;
        u32x2_t hp[4];
        {
            f32x4 c0 = MFMA(a0, lds_wfrag2(wb0, 0), zf);
            c0 = MFMA(a1, lds_wfrag2(wb1, 0), c0);
            f32x4 c1 = MFMA(a0, lds_wfrag2(wb0, 1), zf);
            c1 = MFMA(a1, lds_wfrag2(wb1, 1), c1);
#pragma unroll
            for (int r = 0; r < 4; ++r)
                hp[r].x = cvt2(lrelu(c0[r] + bias_nb[0]), lrelu(c1[r] + bias_nb[1]));
            f32x4 c2 = MFMA(a0, lds_wfrag2(wb0, 2), zf);
            c2 = MFMA(a1, lds_wfrag2(wb1, 2), c2);
            f32x4 c3 = MFMA(a0, lds_wfrag2(wb0, 3), zf);
            c3 = MFMA(a1, lds_wfrag2(wb1, 3), c3);
#pragma unroll
            for (int r = 0; r < 4; ++r)
                hp[r].y = cvt2(lrelu(c2[r] + bias_nb[2]), lrelu(c3[r] + bias_nb[3]));
        }
#pragma unroll
        for (int r = 0; r < 4; ++r)
            *(u32x2a*)(catw + (q * 4 + r) * 68 + 4 * t) = hp[r];   // h slot 4t+nt

        // ---- phase C: scores = h @ (w_attn*log2e); softmax over m via exp2; pool ----
        short8 h0 = lds_afrag(catw, t, 0, q);
        short8 h1 = lds_afrag(catw, t, 1, q);
        const u16* wa0 = watt_base[0] + licm;
        const u16* wa1 = watt_base[1] + licm;
        float pvn = 0.f, pvd = 1.f;
#pragma unroll
        for (int nt = 0; nt < 4; ++nt) {
            f32x4 s = MFMA(h0, lds_wfrag2(wa0, nt), zf);
            s = MFMA(h1, lds_wfrag2(wa1, nt), s);
            float num = 0.f, den = 0.f;
#pragma unroll
            for (int r = 0; r < 4; ++r) {
                u32 pk = (nt < 2) ? hp[r].x : hp[r].y;
                u32 hb = (nt & 1) ? (pk & 0xFFFF0000u) : (pk << 16);
                float e = fexp2(s[r]);      // no max-sub: |score*log2e| << 126
                num = fmaf(e, bits2f(hb), num);
                den += e;
            }
            num += __shfl_xor(num, 16); den += __shfl_xor(den, 16);
            num += __shfl_xor(num, 32); den += __shfl_xor(den, 32);
            // lane only consumes its own q's channel group: select, divide once later
            bool sel = (q == nt);
            pvn = sel ? num : pvn;
            pvd = sel ? den : pvd;
        }
        poolw[p * 68 + q * 16 + t] = cvt1(pvn * frcp(pvd));

        // ---- bottom: convert this iteration's prefetch into the packed carry ----
        gpa.x = cvt2(gb0.x, gb0.y); gpa.y = cvt2(gb0.z, gb0.w);
        gpb.x = cvt2(gb1.x, gb1.y); gpb.y = cvt2(gb1.z, gb1.w);
        rp0 = cvt2(rb0.x, rb0.y); rp1 = cvt2(rb0.z, rb0.w);
        rp2 = cvt2(rb1.x, rb1.y); rp3 = cvt2(rb1.z, rb1.w);
        ixB = ixC;
    }

    // ---- epilogue, fused per-nt (peak ~70 regs, was ~130 with all 12 frags resident:
    //      THAT was the spill driver at every 128-reg budget) ----
    short8 pf0 = lds_afrag(poolw, t, 0, q);
    short8 pf1 = lds_afrag(poolw, t, 1, q);
    U8 sxu;
    {
        const float* fp = fpb + (size_t)(P0 + t) * 32 + q * 8;
        f32x4a v0 = *(const f32x4a*)fp;
        f32x4a v1 = *(const f32x4a*)(fp + 4);
        sxu.w[0] = cvt2(v0.x, v0.y); sxu.w[1] = cvt2(v0.z, v0.w);
        sxu.w[2] = cvt2(v1.x, v1.y); sxu.w[3] = cvt2(v1.z, v1.w);
    }
    short8 scf = sxu.s;
#pragma unroll 1
    for (int nt = 0; nt < 4; ++nt) {
        float2 po = s_pr_out[nt * 16 + t];
        float2 ps = s_pr_sc[nt * 16 + t];
        short8 wo0 = load_bfrag(w_out, 64, 64, 0, nt, q, t, po.x);
        short8 wo1 = load_bfrag(w_out, 64, 64, 1, nt, q, t, po.x);
        short8 ws  = load_bfrag(w_sc, 32, 64, 0, nt, q, t, ps.x);
        float bos = po.y + ps.y;
        f32x4 oa = {bos, bos, bos, bos};
        oa = MFMA(pf0, wo0, oa);
        oa = MFMA(pf1, wo1, oa);
        f32x4 sa = MFMA(scf, ws, zf);
#pragma unroll
        for (int r = 0; r < 4; ++r)
            outp[(size_t)(P0 + q * 4 + r) * 64 + nt * 16 + t] = lrelu(oa[r] + sa[r]);
    }
}

extern "C" void kernel_launch(void* const* d_in, const int* in_sizes, int n_in,
                              void* d_out, int out_size, void* d_ws, size_t ws_size,
                              hipStream_t stream) {
    hipLaunchKernelGGL(lfa_kernel, dim3(2048), dim3(256), 0, stream,
                       d_in[0], d_in[1], (const int*)d_in[2],
                       d_in[3], d_in[4], d_in[5], d_in[6], d_in[7], d_in[8],
                       d_in[9], d_in[10], d_in[11], d_in[12], d_in[13], d_in[14],
                       d_in[15],
                       d_in[16], d_in[17], d_in[18], d_in[19], d_in[20], d_in[21],
                       d_in[22], d_in[23], d_in[24], d_in[25], d_in[26], d_in[27],
                       (float*)d_out);
}

// Round 7
// 275.702 us; speedup vs baseline: 1.0352x; 1.0201x over previous
//
#include <hip/hip_runtime.h>
#include <hip/hip_bf16.h>

typedef unsigned short u16;
typedef unsigned int u32;
typedef __attribute__((ext_vector_type(8))) short short8;
typedef __attribute__((ext_vector_type(4))) float f32x4;

// aliasing-safe types for type-punned global/LDS access
typedef float __attribute__((may_alias)) f32a;
typedef u32 __attribute__((may_alias)) u32a;
typedef __attribute__((ext_vector_type(2))) float f32x2_t;
typedef f32x2_t __attribute__((may_alias)) f32x2a;
typedef __attribute__((ext_vector_type(4))) float f32x4_t;
typedef f32x4_t __attribute__((may_alias)) f32x4a;
typedef __attribute__((ext_vector_type(2))) u32 u32x2_t;
typedef u32x2_t __attribute__((may_alias)) u32x2a;
typedef short8 __attribute__((may_alias)) short8a;

#define NSLOPE 0.2f
#define BNEPS  1e-5f
#define LOG2E  1.4426950408889634f

union U8 { short8 s; u16 u[8]; u32 w[4]; };

__device__ __forceinline__ u16 f2bf_scalar(float f) {
    union { float f; u32 i; } x; x.f = f;
    u32 u = x.i + 0x7FFFu + ((x.i >> 16) & 1u);
    return (u16)(u >> 16);
}

// packed f32x2 -> bf16x2 (RNE). gfx950 has v_cvt_pk_bf16_f32.
__device__ __forceinline__ u32 cvt2(float a, float b) {
#if __has_builtin(__builtin_amdgcn_cvt_pk_bf16_f32)
    auto p = __builtin_amdgcn_cvt_pk_bf16_f32(a, b);
    u32 w; __builtin_memcpy(&w, &p, sizeof(u32));
    return w;
#else
    return (u32)f2bf_scalar(a) | ((u32)f2bf_scalar(b) << 16);
#endif
}
__device__ __forceinline__ u16 cvt1(float a) { return (u16)cvt2(a, a); }

// lrelu = max(x, 0.2x): 2 VALU ops, exact for all x
__device__ __forceinline__ float lrelu(float x) { return fmaxf(x, NSLOPE * x); }

__device__ __forceinline__ float fexp2(float x) {
#if __has_builtin(__builtin_amdgcn_exp2f)
    return __builtin_amdgcn_exp2f(x);   // v_exp_f32 = 2^x
#else
    return exp2f(x);
#endif
}

__device__ __forceinline__ float frcp(float x) {
#if __has_builtin(__builtin_amdgcn_rcpf)
    return __builtin_amdgcn_rcpf(x);    // v_rcp_f32, ~1ulp — fine at this tolerance
#else
    return 1.f / x;
#endif
}

__device__ __forceinline__ float ldf(const void* p, size_t i) { return ((const f32a*)p)[i]; }

// B-fragment for mfma_f32_16x16x32_bf16 from fp32 global W, BN scale folded in:
// lane holds B[k = ks*32 + q*8 + j][n = nt*16 + t] * scale   (epilogue only)
__device__ __forceinline__ short8 load_bfrag(const void* W, int K, int Cn, int ks, int nt,
                                             int q, int t, float scale) {
    U8 x;
#pragma unroll
    for (int j = 0; j < 8; ++j) {
        int k = ks * 32 + q * 8 + j;
        x.u[j] = (k < K) ? f2bf_scalar(ldf(W, (size_t)k * Cn + nt * 16 + t) * scale) : (u16)0;
    }
    return x.s;
}

// A-fragment from per-wave LDS tile row-major [16][68] bf16 — two b64 reads
// (byte addr row*136 + ks*64 + q*16: 8B-aligned). Same-wave DS is in-order.
__device__ __forceinline__ short8 lds_afrag(const u16* buf, int row, int ks, int q) {
    const u16* cp = buf + row * 68 + ks * 32 + q * 8;
    u32x2a a = *(const u32x2a*)cp;
    u32x2a b = *(const u32x2a*)(cp + 4);
    U8 x; x.w[0] = a.x; x.w[1] = a.y; x.w[2] = b.x; x.w[3] = b.y;
    return x.s;
}

// B-fragment from a per-lane weight base (s_w*T + t*64 + swizzled slot for this ks,q):
// one ds_read_b128 at imm offset nt*2048B. XOR slot swizzle keeps a q-group's 16
// lanes spread over all 8 16B slots (2 lanes/bank at the b128 floor = free).
__device__ __forceinline__ short8 lds_wfrag2(const u16* base, int nt) {
    return *(const short8a*)(base + (nt << 10));
}

#define MFMA(a, b, c) __builtin_amdgcn_mfma_f32_16x16x32_bf16((a), (b), (c), 0, 0, 0)

// One wave = one group of 16 points. cat/h/pool tiles are PER-WAVE: no in-loop barriers.
// R13 (on R6's no-spill base: epilogue fused per-nt, waves_per_eu(4,4), 4 blocks/CU):
// VALU-issue-bound at 70% VALUBusy -> cut instruction count:
// (a) load_raw de-masked: wraw rows k=11..31 are EXACT ZEROS, so q>=2 lanes' A-frags and
//     q1's k=11..15 slots may hold finite garbage (0 x finite = 0 in MFMA) — 12->1 cndmask;
// (b) #pragma unroll 2: kills the 8-9 loop-carried phi copies of the packed carry;
// (c) hv kept in f32 for phase C (reg headroom exists: VGPR 60/128) — no unpack bit-ops;
// (d) readfirstlane(wv): proves P0/fb wave-uniform -> SGPR-base addressing.
// Anti-LICM 'licm' keeps weight ds_reads in-loop (R1: LICM rehoists into 64 regs).
__global__
__attribute__((amdgpu_flat_work_group_size(256, 256), amdgpu_waves_per_eu(4, 4)))
void lfa_kernel(
    const void* __restrict__ feat,        // (131072, 32) fp32
    const void* __restrict__ rawf,        // (131072*16, 10) fp32
    const int*  __restrict__ nbidx,       // (131072, 16) int32
    const void* __restrict__ w_raw,
    const void* __restrict__ b_raw, const void* __restrict__ g_raw,
    const void* __restrict__ be_raw, const void* __restrict__ m_raw,
    const void* __restrict__ v_raw,
    const void* __restrict__ w_nb,
    const void* __restrict__ b_nb, const void* __restrict__ g_nb,
    const void* __restrict__ be_nb, const void* __restrict__ m_nb,
    const void* __restrict__ v_nb,
    const void* __restrict__ w_attn,
    const void* __restrict__ w_out,
    const void* __restrict__ b_out, const void* __restrict__ g_out,
    const void* __restrict__ be_out, const void* __restrict__ m_out,
    const void* __restrict__ v_out,
    const void* __restrict__ w_sc,
    const void* __restrict__ b_sc, const void* __restrict__ g_sc,
    const void* __restrict__ be_sc, const void* __restrict__ m_sc,
    const void* __restrict__ v_sc,
    float* __restrict__ outp)             // (131072, 64) fp32
{
    // h tile aliases the cat tile: every iteration fully rewrites cat[0..15][0..63]
    // before phase B reads it, and same-wave DS ops execute in order.
    //
    // K-slot <-> channel permutation (so MFMA outputs pack into contiguous LDS slots):
    //   cat slots  0..31 : gather channel s (identity)
    //   cat slots 32..63 : raw-MLP channel ((s-32)&1)*16 + ((s-32)>>1)   [slot 32+2t+nt]
    //   h   slots  0..63 : h channel (s&3)*16 + (s>>2)                   [slot 4t+nt]
    // s_wnbT rows use the cat permutation; s_wattT rows use the h permutation.
    __shared__ __align__(16) u16 s_cat[4][16 * 68];
    __shared__ __align__(16) u16 s_pool[4][16 * 68];
    __shared__ __align__(16) u16 s_wnbT[64 * 64];    // W_nb^T * s_nb, bf16, swizzled
    __shared__ __align__(16) u16 s_wattT[64 * 64];   // W_attn^T * log2e, bf16, swizzled
    __shared__ float2 s_pr_raw[32];
    __shared__ float2 s_pr_nb[64];
    __shared__ float2 s_pr_out[64];
    __shared__ float2 s_pr_sc[64];

    const int tid  = threadIdx.x;
    const int lane = tid & 63;
    const int wv   = __builtin_amdgcn_readfirstlane(tid >> 6);   // wave-uniform by construction
    const int t    = lane & 15;
    const int q    = lane >> 4;

    // ---- fold BN (+linear bias) into per-channel scale/bias ----
    if (tid < 64) {
        int c = tid;
        float s = ldf(g_nb, c) * rsqrtf(ldf(v_nb, c) + BNEPS);
        s_pr_nb[c] = make_float2(s, (ldf(b_nb, c) - ldf(m_nb, c)) * s + ldf(be_nb, c));
    } else if (tid < 128) {
        int c = tid - 64;
        float s = ldf(g_out, c) * rsqrtf(ldf(v_out, c) + BNEPS);
        s_pr_out[c] = make_float2(s, (ldf(b_out, c) - ldf(m_out, c)) * s + ldf(be_out, c));
    } else if (tid < 192) {
        int c = tid - 128;
        float s = ldf(g_sc, c) * rsqrtf(ldf(v_sc, c) + BNEPS);
        s_pr_sc[c] = make_float2(s, (ldf(b_sc, c) - ldf(m_sc, c)) * s + ldf(be_sc, c));
    } else if (tid < 224) {
        int c = tid - 192;
        float s = ldf(g_raw, c) * rsqrtf(ldf(v_raw, c) + BNEPS);
        s_pr_raw[c] = make_float2(s, (ldf(b_raw, c) - ldf(m_raw, c)) * s + ldf(be_raw, c));
    }
    __syncthreads();

    // ---- cooperative fill of the shared bf16 weight images (coalesced: n fast) ----
#pragma unroll 4
    for (int idx = tid; idx < 64 * 64; idx += 256) {
        int n = idx & 63, s = idx >> 6;    // s = K-slot
        int off = (n << 6) | (((s >> 3) ^ (n & 7)) << 3) | (s & 7);
        int knb = (s < 32) ? s : 32 + (((s - 32) & 1) << 4) + ((s - 32) >> 1);
        int kat = ((s & 3) << 4) + (s >> 2);
        s_wnbT[off]  = f2bf_scalar(ldf(w_nb,   (size_t)knb * 64 + n) * s_pr_nb[n].x);
        s_wattT[off] = f2bf_scalar(ldf(w_attn, (size_t)kat * 64 + n) * LOG2E);
    }
    __syncthreads();   // last block-wide barrier

    // ---- small loop-resident state: raw weights (scale folded; BN bias in row 10) ----
    short8 wraw[2];
    float bias_nb[4];
#pragma unroll
    for (int nt = 0; nt < 2; ++nt) {
        int c = nt * 16 + t;
        float2 pr = s_pr_raw[c];
        U8 x;
#pragma unroll
        for (int j = 0; j < 8; ++j) {
            int k = q * 8 + j;
            float v = (k < 10) ? ldf(w_raw, (size_t)k * 32 + c) * pr.x
                               : (k == 10 ? pr.y : 0.f);
            x.u[j] = f2bf_scalar(v);
        }
        wraw[nt] = x.s;
    }
#pragma unroll
    for (int nt = 0; nt < 4; ++nt) bias_nb[nt] = s_pr_nb[nt * 16 + t].y;

    // per-lane swizzled weight bases (iter-invariant; frag read = base + nt*2048B imm)
    const u16* wnb_base[2];
    const u16* watt_base[2];
#pragma unroll
    for (int ks = 0; ks < 2; ++ks) {
        int lane_off = (t << 6) + ((((ks << 2) | q) ^ (t & 7)) << 3);
        wnb_base[ks]  = s_wnbT  + lane_off;
        watt_base[ks] = s_wattT + lane_off;
    }

    u16* catw  = &s_cat[wv][0];
    u16* poolw = &s_pool[wv][0];

    const f32x4 zf = {0.f, 0.f, 0.f, 0.f};
    const int g  = blockIdx.x * 4 + wv;     // 8192 groups, grid 2048 x 4 waves
    const int P0 = g * 16;
    const int bb = P0 >> 16;                // group never straddles batch boundary
    const size_t fb = (size_t)bb << 16;

    const int m_ = lane >> 2;               // gather: neighbor index this lane handles
    const int pc = lane & 3;                // gather: 8-float piece

    // hoisted per-wave base pointers
    const int*  nbp  = nbidx + P0 * 16 + m_;                       // idx for point p: nbp[p*16]
    const f32a* rawp = (const f32a*)rawf + (size_t)P0 * 160 + (size_t)t * 10;  // + p*160
    const float* fpb = (const float*)feat;

    const bool q_eq1 = (q == 1);

    // branch-free loaders -> SSA f32x4 pairs (no structs: avoid private-stack demotion)
    auto load_gather = [&](int ix, f32x4& a, f32x4& b) {
        const float* fp = fpb + (fb + (size_t)ix) * 32 + pc * 8;
        a = *(const f32x4a*)fp;
        b = *(const f32x4a*)(fp + 4);
    };
    // lane(t,q) supplies raw[t][k], k=q*8+j; rows are 10 floats. q0 reads f0..7;
    // q1 reads f8..9 (b64 at +8) and injects bias-carrier 1.0 at k=10. All OTHER
    // slots (q1 k=11..15, all of q2/q3 k=16..31) multiply EXACT-ZERO wraw rows in
    // the MFMA, so they may hold finite garbage — no masking needed (0 x finite = 0).
    auto load_raw = [&](int p, f32x4& a, f32x4& b) {
        const f32a* rp = rawp + (size_t)p * 160;
        f32x2a L0 = *(const f32x2a*)(rp + ((q & 1) << 3));  // q0:f01  q1:f89
        f32x2a L1 = *(const f32x2a*)(rp + 2);
        f32x2a L2 = *(const f32x2a*)(rp + 4);
        f32x2a L3 = *(const f32x2a*)(rp + 6);
        a.x = L0.x;
        a.y = L0.y;
        a.z = q_eq1 ? 1.f : L1.x;           // k=10 bias carrier for q1
        a.w = L1.y;
        b.x = L2.x; b.y = L2.y;
        b.z = L3.x; b.w = L3.y;
    };

    // ---- software-pipeline preamble: loop-carried state is PACKED bf16 (8 u32) ----
    u32x2_t gpa, gpb;       // gather row, bf16x2 packed (lo 4, hi 4)
    u32 rp0, rp1, rp2, rp3; // raw-MLP A fragment, packed
    {
        int ixA = nbp[0];
        f32x4 g0, g1, r0, r1;
        load_gather(ixA, g0, g1);
        load_raw(0, r0, r1);
        gpa.x = cvt2(g0.x, g0.y); gpa.y = cvt2(g0.z, g0.w);
        gpb.x = cvt2(g1.x, g1.y); gpb.y = cvt2(g1.z, g1.w);
        rp0 = cvt2(r0.x, r0.y); rp1 = cvt2(r0.z, r0.w);
        rp2 = cvt2(r1.x, r1.y); rp3 = cvt2(r1.z, r1.w);
    }
    int ixB = nbp[16];
    int licm = 0;   // always 0; opaque to the compiler (anti-LICM for weight reads)

#pragma unroll 2
    for (int p = 0; p < 16; ++p) {
        asm volatile("" : "+v"(licm));

        // next-next neighbor index (1 reg, cheap; full-body latency cover)
        const int pnn = (p + 2 < 16) ? p + 2 : 15;
        int ixC = nbp[pnn * 16];

        // ---- phase A: gather -> cat[m][0..31] (carried packed, b64 LDS writes) ----
        *(u32x2a*)(catw + m_ * 68 + pc * 8)     = gpa;
        *(u32x2a*)(catw + m_ * 68 + pc * 8 + 4) = gpb;

        // ---- raw MLP via MFMA (bias in row 10) -> cat slots 32+2t+nt (packed b32) ----
        {
            U8 au;
            au.w[0] = rp0; au.w[1] = rp1; au.w[2] = rp2; au.w[3] = rp3;
            short8 ar = au.s;
            f32x4 racc0 = MFMA(ar, wraw[0], zf);
            f32x4 racc1 = MFMA(ar, wraw[1], zf);
#pragma unroll
            for (int r = 0; r < 4; ++r) {
                u32 wpk = cvt2(lrelu(racc0[r]), lrelu(racc1[r]));
                *(u32a*)(catw + (q * 4 + r) * 68 + 32 + 2 * t) = wpk;
            }
        }

        // ---- MID-BODY prefetch issue: carried regs now dead; loads cover phases B+C ----
        const int pn = (p + 1 < 16) ? p + 1 : 15;
        f32x4 gb0, gb1, rb0, rb1;
        load_gather(ixB, gb0, gb1);
        load_raw(pn, rb0, rb1);

        // ---- phase B: h = lrelu(cat @ (w_nb*s) + bias); hv stays f32 for phase C,
        //      hp = packed words for the LDS write (reg headroom covers both) ----
        short8 a0 = lds_afrag(catw, t, 0, q);
        short8 a1 = lds_afrag(catw, t, 1, q);
        const u16* wb0 = wnb_base[0] + licm;
        const u16* wb1 = wnb_base[1] + licm;
        float hv[4][4];
        {
            f32x4 c0 = MFMA(a0, lds_wfrag2(wb0, 0), zf);
            c0 = MFMA(a1, lds_wfrag2(wb1, 0), c0);
            f32x4 c1 = MFMA(a0, lds_wfrag2(wb0, 1), zf);
            c1 = MFMA(a1, lds_wfrag2(wb1, 1), c1);
            f32x4 c2 = MFMA(a0, lds_wfrag2(wb0, 2), zf);
            c2 = MFMA(a1, lds_wfrag2(wb1, 2), c2);
            f32x4 c3 = MFMA(a0, lds_wfrag2(wb0, 3), zf);
            c3 = MFMA(a1, lds_wfrag2(wb1, 3), c3);
#pragma unroll
            for (int r = 0; r < 4; ++r) {
                hv[0][r] = lrelu(c0[r] + bias_nb[0]);
                hv[1][r] = lrelu(c1[r] + bias_nb[1]);
                hv[2][r] = lrelu(c2[r] + bias_nb[2]);
                hv[3][r] = lrelu(c3[r] + bias_nb[3]);
            }
        }
#pragma unroll
        for (int r = 0; r < 4; ++r) {
            u32x2_t w2;
            w2.x = cvt2(hv[0][r], hv[1][r]);
            w2.y = cvt2(hv[2][r], hv[3][r]);
            *(u32x2a*)(catw + (q * 4 + r) * 68 + 4 * t) = w2;   // h slot 4t+nt
        }

        // ---- phase C: scores = h @ (w_attn*log2e); softmax over m via exp2; pool ----
        short8 h0 = lds_afrag(catw, t, 0, q);
        short8 h1 = lds_afrag(catw, t, 1, q);
        const u16* wa0 = watt_base[0] + licm;
        const u16* wa1 = watt_base[1] + licm;
        float pvn = 0.f, pvd = 1.f;
#pragma unroll
        for (int nt = 0; nt < 4; ++nt) {
            f32x4 s = MFMA(h0, lds_wfrag2(wa0, nt), zf);
            s = MFMA(h1, lds_wfrag2(wa1, nt), s);
            float num = 0.f, den = 0.f;
#pragma unroll
            for (int r = 0; r < 4; ++r) {
                float e = fexp2(s[r]);      // no max-sub: |score*log2e| << 126
                num = fmaf(e, hv[nt][r], num);
                den += e;
            }
            num += __shfl_xor(num, 16); den += __shfl_xor(den, 16);
            num += __shfl_xor(num, 32); den += __shfl_xor(den, 32);
            // lane only consumes its own q's channel group: select, divide once later
            bool sel = (q == nt);
            pvn = sel ? num : pvn;
            pvd = sel ? den : pvd;
        }
        poolw[p * 68 + q * 16 + t] = cvt1(pvn * frcp(pvd));

        // ---- bottom: convert this iteration's prefetch into the packed carry ----
        gpa.x = cvt2(gb0.x, gb0.y); gpa.y = cvt2(gb0.z, gb0.w);
        gpb.x = cvt2(gb1.x, gb1.y); gpb.y = cvt2(gb1.z, gb1.w);
        rp0 = cvt2(rb0.x, rb0.y); rp1 = cvt2(rb0.z, rb0.w);
        rp2 = cvt2(rb1.x, rb1.y); rp3 = cvt2(rb1.z, rb1.w);
        ixB = ixC;
    }

    // ---- epilogue, fused per-nt (peak ~70 regs; R6 fix — full-resident frags were
    //      the spill driver at every 128-reg budget) ----
    short8 pf0 = lds_afrag(poolw, t, 0, q);
    short8 pf1 = lds_afrag(poolw, t, 1, q);
    U8 sxu;
    {
        const float* fp = fpb + (size_t)(P0 + t) * 32 + q * 8;
        f32x4a v0 = *(const f32x4a*)fp;
        f32x4a v1 = *(const f32x4a*)(fp + 4);
        sxu.w[0] = cvt2(v0.x, v0.y); sxu.w[1] = cvt2(v0.z, v0.w);
        sxu.w[2] = cvt2(v1.x, v1.y); sxu.w[3] = cvt2(v1.z, v1.w);
    }
    short8 scf = sxu.s;
#pragma unroll 1
    for (int nt = 0; nt < 4; ++nt) {
        float2 po = s_pr_out[nt * 16 + t];
        float2 ps = s_pr_sc[nt * 16 + t];
        short8 wo0 = load_bfrag(w_out, 64, 64, 0, nt, q, t, po.x);
        short8 wo1 = load_bfrag(w_out, 64, 64, 1, nt, q, t, po.x);
        short8 ws  = load_bfrag(w_sc, 32, 64, 0, nt, q, t, ps.x);
        float bos = po.y + ps.y;
        f32x4 oa = {bos, bos, bos, bos};
        oa = MFMA(pf0, wo0, oa);
        oa = MFMA(pf1, wo1, oa);
        f32x4 sa = MFMA(scf, ws, zf);
#pragma unroll
        for (int r = 0; r < 4; ++r)
            outp[(size_t)(P0 + q * 4 + r) * 64 + nt * 16 + t] = lrelu(oa[r] + sa[r]);
    }
}

extern "C" void kernel_launch(void* const* d_in, const int* in_sizes, int n_in,
                              void* d_out, int out_size, void* d_ws, size_t ws_size,
                              hipStream_t stream) {
    hipLaunchKernelGGL(lfa_kernel, dim3(2048), dim3(256), 0, stream,
                       d_in[0], d_in[1], (const int*)d_in[2],
                       d_in[3], d_in[4], d_in[5], d_in[6], d_in[7], d_in[8],
                       d_in[9], d_in[10], d_in[11], d_in[12], d_in[13], d_in[14],
                       d_in[15],
                       d_in[16], d_in[17], d_in[18], d_in[19], d_in[20], d_in[21],
                       d_in[22], d_in[23], d_in[24], d_in[25], d_in[26], d_in[27],
                       (float*)d_out);
}

// Round 8
// 269.766 us; speedup vs baseline: 1.0580x; 1.0220x over previous
//
#include <hip/hip_runtime.h>
#include <hip/hip_bf16.h>

typedef unsigned short u16;
typedef unsigned int u32;
typedef __attribute__((ext_vector_type(8))) short short8;
typedef __attribute__((ext_vector_type(4))) float f32x4;

// aliasing-safe types for type-punned global/LDS access
typedef float __attribute__((may_alias)) f32a;
typedef u32 __attribute__((may_alias)) u32a;
typedef __attribute__((ext_vector_type(2))) float f32x2_t;
typedef f32x2_t __attribute__((may_alias)) f32x2a;
typedef __attribute__((ext_vector_type(4))) float f32x4_t;
typedef f32x4_t __attribute__((may_alias)) f32x4a;
typedef __attribute__((ext_vector_type(2))) u32 u32x2_t;
typedef u32x2_t __attribute__((may_alias)) u32x2a;
typedef short8 __attribute__((may_alias)) short8a;

#define NSLOPE 0.2f
#define BNEPS  1e-5f
#define LOG2E  1.4426950408889634f

union U8 { short8 s; u16 u[8]; u32 w[4]; };

__device__ __forceinline__ u16 f2bf_scalar(float f) {
    union { float f; u32 i; } x; x.f = f;
    u32 u = x.i + 0x7FFFu + ((x.i >> 16) & 1u);
    return (u16)(u >> 16);
}

// packed f32x2 -> bf16x2 (RNE). gfx950 has v_cvt_pk_bf16_f32.
__device__ __forceinline__ u32 cvt2(float a, float b) {
#if __has_builtin(__builtin_amdgcn_cvt_pk_bf16_f32)
    auto p = __builtin_amdgcn_cvt_pk_bf16_f32(a, b);
    u32 w; __builtin_memcpy(&w, &p, sizeof(u32));
    return w;
#else
    return (u32)f2bf_scalar(a) | ((u32)f2bf_scalar(b) << 16);
#endif
}
__device__ __forceinline__ u16 cvt1(float a) { return (u16)cvt2(a, a); }

// lrelu = max(x, 0.2x): 2 VALU ops, exact for all x
__device__ __forceinline__ float lrelu(float x) { return fmaxf(x, NSLOPE * x); }

__device__ __forceinline__ float fexp2(float x) {
#if __has_builtin(__builtin_amdgcn_exp2f)
    return __builtin_amdgcn_exp2f(x);   // v_exp_f32 = 2^x
#else
    return exp2f(x);
#endif
}

__device__ __forceinline__ float frcp(float x) {
#if __has_builtin(__builtin_amdgcn_rcpf)
    return __builtin_amdgcn_rcpf(x);    // v_rcp_f32, ~1ulp — fine at this tolerance
#else
    return 1.f / x;
#endif
}

__device__ __forceinline__ float ldf(const void* p, size_t i) { return ((const f32a*)p)[i]; }

// B-fragment for mfma_f32_16x16x32_bf16 from fp32 global W, BN scale folded in:
// lane holds B[k = ks*32 + q*8 + j][n = nt*16 + t] * scale   (epilogue only)
__device__ __forceinline__ short8 load_bfrag(const void* W, int K, int Cn, int ks, int nt,
                                             int q, int t, float scale) {
    U8 x;
#pragma unroll
    for (int j = 0; j < 8; ++j) {
        int k = ks * 32 + q * 8 + j;
        x.u[j] = (k < K) ? f2bf_scalar(ldf(W, (size_t)k * Cn + nt * 16 + t) * scale) : (u16)0;
    }
    return x.s;
}

// A-fragment from per-wave LDS tile row-major [16][68] bf16 — two b64 reads
// (byte addr row*136 + ks*64 + q*16: 8B-aligned). Same-wave DS is in-order.
__device__ __forceinline__ short8 lds_afrag(const u16* buf, int row, int ks, int q) {
    const u16* cp = buf + row * 68 + ks * 32 + q * 8;
    u32x2a a = *(const u32x2a*)cp;
    u32x2a b = *(const u32x2a*)(cp + 4);
    U8 x; x.w[0] = a.x; x.w[1] = a.y; x.w[2] = b.x; x.w[3] = b.y;
    return x.s;
}

// B-fragment from a per-lane weight base (s_w*T + t*64 + swizzled slot for this ks,q):
// one ds_read_b128 at imm offset nt*2048B. XOR slot swizzle keeps a q-group's 16
// lanes spread over all 8 16B slots (2 lanes/bank at the b128 floor = free).
__device__ __forceinline__ short8 lds_wfrag2(const u16* base, int nt) {
    return *(const short8a*)(base + (nt << 10));
}

#define MFMA(a, b, c) __builtin_amdgcn_mfma_f32_16x16x32_bf16((a), (b), (c), 0, 0, 0)

// One wave = one group of 16 points. cat/h/pool tiles are PER-WAVE: no in-loop barriers.
// R14 (on R7's lean base: 56 VGPR, no spill): occupancy was LDS-capped, not reg-capped —
// 256-thread blocks duplicated the 16KB weight images for only 4 waves (35.8KB -> 4
// blocks = 16 waves/CU, 50% cap). Switch to 512-thread blocks (8 waves): LDS 53KB ->
// 3 blocks/CU = 24 waves/CU (75% cap). waves_per_eu(6,6) budget ~85 regs (>56 used).
// Sentinels: WRITE=32.8MB (spill), Occupancy (block fit). All R7 structure unchanged:
// de-masked load_raw (wraw k=11..31 exact zeros -> garbage x 0 = 0), unroll 2, f32 hv,
// epilogue fused per-nt, anti-LICM 'licm', slot-permuted packed LDS writes,
// select-then-rcp softmax, bias-in-row-10.
__global__
__attribute__((amdgpu_flat_work_group_size(512, 512), amdgpu_waves_per_eu(6, 6)))
void lfa_kernel(
    const void* __restrict__ feat,        // (131072, 32) fp32
    const void* __restrict__ rawf,        // (131072*16, 10) fp32
    const int*  __restrict__ nbidx,       // (131072, 16) int32
    const void* __restrict__ w_raw,
    const void* __restrict__ b_raw, const void* __restrict__ g_raw,
    const void* __restrict__ be_raw, const void* __restrict__ m_raw,
    const void* __restrict__ v_raw,
    const void* __restrict__ w_nb,
    const void* __restrict__ b_nb, const void* __restrict__ g_nb,
    const void* __restrict__ be_nb, const void* __restrict__ m_nb,
    const void* __restrict__ v_nb,
    const void* __restrict__ w_attn,
    const void* __restrict__ w_out,
    const void* __restrict__ b_out, const void* __restrict__ g_out,
    const void* __restrict__ be_out, const void* __restrict__ m_out,
    const void* __restrict__ v_out,
    const void* __restrict__ w_sc,
    const void* __restrict__ b_sc, const void* __restrict__ g_sc,
    const void* __restrict__ be_sc, const void* __restrict__ m_sc,
    const void* __restrict__ v_sc,
    float* __restrict__ outp)             // (131072, 64) fp32
{
    // h tile aliases the cat tile: every iteration fully rewrites cat[0..15][0..63]
    // before phase B reads it, and same-wave DS ops execute in order.
    //
    // K-slot <-> channel permutation (so MFMA outputs pack into contiguous LDS slots):
    //   cat slots  0..31 : gather channel s (identity)
    //   cat slots 32..63 : raw-MLP channel ((s-32)&1)*16 + ((s-32)>>1)   [slot 32+2t+nt]
    //   h   slots  0..63 : h channel (s&3)*16 + (s>>2)                   [slot 4t+nt]
    // s_wnbT rows use the cat permutation; s_wattT rows use the h permutation.
    __shared__ __align__(16) u16 s_cat[8][16 * 68];
    __shared__ __align__(16) u16 s_pool[8][16 * 68];
    __shared__ __align__(16) u16 s_wnbT[64 * 64];    // W_nb^T * s_nb, bf16, swizzled
    __shared__ __align__(16) u16 s_wattT[64 * 64];   // W_attn^T * log2e, bf16, swizzled
    __shared__ float2 s_pr_raw[32];
    __shared__ float2 s_pr_nb[64];
    __shared__ float2 s_pr_out[64];
    __shared__ float2 s_pr_sc[64];

    const int tid  = threadIdx.x;
    const int lane = tid & 63;
    const int wv   = __builtin_amdgcn_readfirstlane(tid >> 6);   // wave-uniform by construction
    const int t    = lane & 15;
    const int q    = lane >> 4;

    // ---- fold BN (+linear bias) into per-channel scale/bias ----
    if (tid < 64) {
        int c = tid;
        float s = ldf(g_nb, c) * rsqrtf(ldf(v_nb, c) + BNEPS);
        s_pr_nb[c] = make_float2(s, (ldf(b_nb, c) - ldf(m_nb, c)) * s + ldf(be_nb, c));
    } else if (tid < 128) {
        int c = tid - 64;
        float s = ldf(g_out, c) * rsqrtf(ldf(v_out, c) + BNEPS);
        s_pr_out[c] = make_float2(s, (ldf(b_out, c) - ldf(m_out, c)) * s + ldf(be_out, c));
    } else if (tid < 192) {
        int c = tid - 128;
        float s = ldf(g_sc, c) * rsqrtf(ldf(v_sc, c) + BNEPS);
        s_pr_sc[c] = make_float2(s, (ldf(b_sc, c) - ldf(m_sc, c)) * s + ldf(be_sc, c));
    } else if (tid < 224) {
        int c = tid - 192;
        float s = ldf(g_raw, c) * rsqrtf(ldf(v_raw, c) + BNEPS);
        s_pr_raw[c] = make_float2(s, (ldf(b_raw, c) - ldf(m_raw, c)) * s + ldf(be_raw, c));
    }
    __syncthreads();

    // ---- cooperative fill of the shared bf16 weight images (coalesced: n fast) ----
#pragma unroll 4
    for (int idx = tid; idx < 64 * 64; idx += 512) {
        int n = idx & 63, s = idx >> 6;    // s = K-slot
        int off = (n << 6) | (((s >> 3) ^ (n & 7)) << 3) | (s & 7);
        int knb = (s < 32) ? s : 32 + (((s - 32) & 1) << 4) + ((s - 32) >> 1);
        int kat = ((s & 3) << 4) + (s >> 2);
        s_wnbT[off]  = f2bf_scalar(ldf(w_nb,   (size_t)knb * 64 + n) * s_pr_nb[n].x);
        s_wattT[off] = f2bf_scalar(ldf(w_attn, (size_t)kat * 64 + n) * LOG2E);
    }
    __syncthreads();   // last block-wide barrier

    // ---- small loop-resident state: raw weights (scale folded; BN bias in row 10) ----
    short8 wraw[2];
    float bias_nb[4];
#pragma unroll
    for (int nt = 0; nt < 2; ++nt) {
        int c = nt * 16 + t;
        float2 pr = s_pr_raw[c];
        U8 x;
#pragma unroll
        for (int j = 0; j < 8; ++j) {
            int k = q * 8 + j;
            float v = (k < 10) ? ldf(w_raw, (size_t)k * 32 + c) * pr.x
                               : (k == 10 ? pr.y : 0.f);
            x.u[j] = f2bf_scalar(v);
        }
        wraw[nt] = x.s;
    }
#pragma unroll
    for (int nt = 0; nt < 4; ++nt) bias_nb[nt] = s_pr_nb[nt * 16 + t].y;

    // per-lane swizzled weight bases (iter-invariant; frag read = base + nt*2048B imm)
    const u16* wnb_base[2];
    const u16* watt_base[2];
#pragma unroll
    for (int ks = 0; ks < 2; ++ks) {
        int lane_off = (t << 6) + ((((ks << 2) | q) ^ (t & 7)) << 3);
        wnb_base[ks]  = s_wnbT  + lane_off;
        watt_base[ks] = s_wattT + lane_off;
    }

    u16* catw  = &s_cat[wv][0];
    u16* poolw = &s_pool[wv][0];

    const f32x4 zf = {0.f, 0.f, 0.f, 0.f};
    const int g  = blockIdx.x * 8 + wv;     // 8192 groups, grid 1024 x 8 waves
    const int P0 = g * 16;
    const int bb = P0 >> 16;                // group never straddles batch boundary
    const size_t fb = (size_t)bb << 16;

    const int m_ = lane >> 2;               // gather: neighbor index this lane handles
    const int pc = lane & 3;                // gather: 8-float piece

    // hoisted per-wave base pointers
    const int*  nbp  = nbidx + P0 * 16 + m_;                       // idx for point p: nbp[p*16]
    const f32a* rawp = (const f32a*)rawf + (size_t)P0 * 160 + (size_t)t * 10;  // + p*160
    const float* fpb = (const float*)feat;

    const bool q_eq1 = (q == 1);

    // branch-free loaders -> SSA f32x4 pairs (no structs: avoid private-stack demotion)
    auto load_gather = [&](int ix, f32x4& a, f32x4& b) {
        const float* fp = fpb + (fb + (size_t)ix) * 32 + pc * 8;
        a = *(const f32x4a*)fp;
        b = *(const f32x4a*)(fp + 4);
    };
    // lane(t,q) supplies raw[t][k], k=q*8+j; rows are 10 floats. q0 reads f0..7;
    // q1 reads f8..9 (b64 at +8) and injects bias-carrier 1.0 at k=10. All OTHER
    // slots (q1 k=11..15, all of q2/q3 k=16..31) multiply EXACT-ZERO wraw rows in
    // the MFMA, so they may hold finite garbage — no masking needed (0 x finite = 0).
    auto load_raw = [&](int p, f32x4& a, f32x4& b) {
        const f32a* rp = rawp + (size_t)p * 160;
        f32x2a L0 = *(const f32x2a*)(rp + ((q & 1) << 3));  // q0:f01  q1:f89
        f32x2a L1 = *(const f32x2a*)(rp + 2);
        f32x2a L2 = *(const f32x2a*)(rp + 4);
        f32x2a L3 = *(const f32x2a*)(rp + 6);
        a.x = L0.x;
        a.y = L0.y;
        a.z = q_eq1 ? 1.f : L1.x;           // k=10 bias carrier for q1
        a.w = L1.y;
        b.x = L2.x; b.y = L2.y;
        b.z = L3.x; b.w = L3.y;
    };

    // ---- software-pipeline preamble: loop-carried state is PACKED bf16 (8 u32) ----
    u32x2_t gpa, gpb;       // gather row, bf16x2 packed (lo 4, hi 4)
    u32 rp0, rp1, rp2, rp3; // raw-MLP A fragment, packed
    {
        int ixA = nbp[0];
        f32x4 g0, g1, r0, r1;
        load_gather(ixA, g0, g1);
        load_raw(0, r0, r1);
        gpa.x = cvt2(g0.x, g0.y); gpa.y = cvt2(g0.z, g0.w);
        gpb.x = cvt2(g1.x, g1.y); gpb.y = cvt2(g1.z, g1.w);
        rp0 = cvt2(r0.x, r0.y); rp1 = cvt2(r0.z, r0.w);
        rp2 = cvt2(r1.x, r1.y); rp3 = cvt2(r1.z, r1.w);
    }
    int ixB = nbp[16];
    int licm = 0;   // always 0; opaque to the compiler (anti-LICM for weight reads)

#pragma unroll 2
    for (int p = 0; p < 16; ++p) {
        asm volatile("" : "+v"(licm));

        // next-next neighbor index (1 reg, cheap; full-body latency cover)
        const int pnn = (p + 2 < 16) ? p + 2 : 15;
        int ixC = nbp[pnn * 16];

        // ---- phase A: gather -> cat[m][0..31] (carried packed, b64 LDS writes) ----
        *(u32x2a*)(catw + m_ * 68 + pc * 8)     = gpa;
        *(u32x2a*)(catw + m_ * 68 + pc * 8 + 4) = gpb;

        // ---- raw MLP via MFMA (bias in row 10) -> cat slots 32+2t+nt (packed b32) ----
        {
            U8 au;
            au.w[0] = rp0; au.w[1] = rp1; au.w[2] = rp2; au.w[3] = rp3;
            short8 ar = au.s;
            f32x4 racc0 = MFMA(ar, wraw[0], zf);
            f32x4 racc1 = MFMA(ar, wraw[1], zf);
#pragma unroll
            for (int r = 0; r < 4; ++r) {
                u32 wpk = cvt2(lrelu(racc0[r]), lrelu(racc1[r]));
                *(u32a*)(catw + (q * 4 + r) * 68 + 32 + 2 * t) = wpk;
            }
        }

        // ---- MID-BODY prefetch issue: carried regs now dead; loads cover phases B+C ----
        const int pn = (p + 1 < 16) ? p + 1 : 15;
        f32x4 gb0, gb1, rb0, rb1;
        load_gather(ixB, gb0, gb1);
        load_raw(pn, rb0, rb1);

        // ---- phase B: h = lrelu(cat @ (w_nb*s) + bias); hv stays f32 for phase C,
        //      hp = packed words for the LDS write ----
        short8 a0 = lds_afrag(catw, t, 0, q);
        short8 a1 = lds_afrag(catw, t, 1, q);
        const u16* wb0 = wnb_base[0] + licm;
        const u16* wb1 = wnb_base[1] + licm;
        float hv[4][4];
        {
            f32x4 c0 = MFMA(a0, lds_wfrag2(wb0, 0), zf);
            c0 = MFMA(a1, lds_wfrag2(wb1, 0), c0);
            f32x4 c1 = MFMA(a0, lds_wfrag2(wb0, 1), zf);
            c1 = MFMA(a1, lds_wfrag2(wb1, 1), c1);
            f32x4 c2 = MFMA(a0, lds_wfrag2(wb0, 2), zf);
            c2 = MFMA(a1, lds_wfrag2(wb1, 2), c2);
            f32x4 c3 = MFMA(a0, lds_wfrag2(wb0, 3), zf);
            c3 = MFMA(a1, lds_wfrag2(wb1, 3), c3);
#pragma unroll
            for (int r = 0; r < 4; ++r) {
                hv[0][r] = lrelu(c0[r] + bias_nb[0]);
                hv[1][r] = lrelu(c1[r] + bias_nb[1]);
                hv[2][r] = lrelu(c2[r] + bias_nb[2]);
                hv[3][r] = lrelu(c3[r] + bias_nb[3]);
            }
        }
#pragma unroll
        for (int r = 0; r < 4; ++r) {
            u32x2_t w2;
            w2.x = cvt2(hv[0][r], hv[1][r]);
            w2.y = cvt2(hv[2][r], hv[3][r]);
            *(u32x2a*)(catw + (q * 4 + r) * 68 + 4 * t) = w2;   // h slot 4t+nt
        }

        // ---- phase C: scores = h @ (w_attn*log2e); softmax over m via exp2; pool ----
        short8 h0 = lds_afrag(catw, t, 0, q);
        short8 h1 = lds_afrag(catw, t, 1, q);
        const u16* wa0 = watt_base[0] + licm;
        const u16* wa1 = watt_base[1] + licm;
        float pvn = 0.f, pvd = 1.f;
#pragma unroll
        for (int nt = 0; nt < 4; ++nt) {
            f32x4 s = MFMA(h0, lds_wfrag2(wa0, nt), zf);
            s = MFMA(h1, lds_wfrag2(wa1, nt), s);
            float num = 0.f, den = 0.f;
#pragma unroll
            for (int r = 0; r < 4; ++r) {
                float e = fexp2(s[r]);      // no max-sub: |score*log2e| << 126
                num = fmaf(e, hv[nt][r], num);
                den += e;
            }
            num += __shfl_xor(num, 16); den += __shfl_xor(den, 16);
            num += __shfl_xor(num, 32); den += __shfl_xor(den, 32);
            // lane only consumes its own q's channel group: select, divide once later
            bool sel = (q == nt);
            pvn = sel ? num : pvn;
            pvd = sel ? den : pvd;
        }
        poolw[p * 68 + q * 16 + t] = cvt1(pvn * frcp(pvd));

        // ---- bottom: convert this iteration's prefetch into the packed carry ----
        gpa.x = cvt2(gb0.x, gb0.y); gpa.y = cvt2(gb0.z, gb0.w);
        gpb.x = cvt2(gb1.x, gb1.y); gpb.y = cvt2(gb1.z, gb1.w);
        rp0 = cvt2(rb0.x, rb0.y); rp1 = cvt2(rb0.z, rb0.w);
        rp2 = cvt2(rb1.x, rb1.y); rp3 = cvt2(rb1.z, rb1.w);
        ixB = ixC;
    }

    // ---- epilogue, fused per-nt (peak ~70 regs; R6 fix — full-resident frags were
    //      the spill driver at every 128-reg budget) ----
    short8 pf0 = lds_afrag(poolw, t, 0, q);
    short8 pf1 = lds_afrag(poolw, t, 1, q);
    U8 sxu;
    {
        const float* fp = fpb + (size_t)(P0 + t) * 32 + q * 8;
        f32x4a v0 = *(const f32x4a*)fp;
        f32x4a v1 = *(const f32x4a*)(fp + 4);
        sxu.w[0] = cvt2(v0.x, v0.y); sxu.w[1] = cvt2(v0.z, v0.w);
        sxu.w[2] = cvt2(v1.x, v1.y); sxu.w[3] = cvt2(v1.z, v1.w);
    }
    short8 scf = sxu.s;
#pragma unroll 1
    for (int nt = 0; nt < 4; ++nt) {
        float2 po = s_pr_out[nt * 16 + t];
        float2 ps = s_pr_sc[nt * 16 + t];
        short8 wo0 = load_bfrag(w_out, 64, 64, 0, nt, q, t, po.x);
        short8 wo1 = load_bfrag(w_out, 64, 64, 1, nt, q, t, po.x);
        short8 ws  = load_bfrag(w_sc, 32, 64, 0, nt, q, t, ps.x);
        float bos = po.y + ps.y;
        f32x4 oa = {bos, bos, bos, bos};
        oa = MFMA(pf0, wo0, oa);
        oa = MFMA(pf1, wo1, oa);
        f32x4 sa = MFMA(scf, ws, zf);
#pragma unroll
        for (int r = 0; r < 4; ++r)
            outp[(size_t)(P0 + q * 4 + r) * 64 + nt * 16 + t] = lrelu(oa[r] + sa[r]);
    }
}

extern "C" void kernel_launch(void* const* d_in, const int* in_sizes, int n_in,
                              void* d_out, int out_size, void* d_ws, size_t ws_size,
                              hipStream_t stream) {
    hipLaunchKernelGGL(lfa_kernel, dim3(1024), dim3(512), 0, stream,
                       d_in[0], d_in[1], (const int*)d_in[2],
                       d_in[3], d_in[4], d_in[5], d_in[6], d_in[7], d_in[8],
                       d_in[9], d_in[10], d_in[11], d_in[12], d_in[13], d_in[14],
                       d_in[15],
                       d_in[16], d_in[17], d_in[18], d_in[19], d_in[20], d_in[21],
                       d_in[22], d_in[23], d_in[24], d_in[25], d_in[26], d_in[27],
                       (float*)d_out);
}

// Round 9
// 268.680 us; speedup vs baseline: 1.0622x; 1.0040x over previous
//
#include <hip/hip_runtime.h>
#include <hip/hip_bf16.h>

typedef unsigned short u16;
typedef unsigned int u32;
typedef __attribute__((ext_vector_type(8))) short short8;
typedef __attribute__((ext_vector_type(4))) float f32x4;

// aliasing-safe types for type-punned global/LDS access
typedef float __attribute__((may_alias)) f32a;
typedef u32 __attribute__((may_alias)) u32a;
typedef __attribute__((ext_vector_type(2))) float f32x2_t;
typedef f32x2_t __attribute__((may_alias)) f32x2a;
typedef __attribute__((ext_vector_type(4))) float f32x4_t;
typedef f32x4_t __attribute__((may_alias)) f32x4a;
typedef __attribute__((ext_vector_type(2))) u32 u32x2_t;
typedef u32x2_t __attribute__((may_alias)) u32x2a;
typedef short8 __attribute__((may_alias)) short8a;

#define NSLOPE 0.2f
#define BNEPS  1e-5f
#define LOG2E  1.4426950408889634f

union U8 { short8 s; u16 u[8]; u32 w[4]; };

__device__ __forceinline__ u16 f2bf_scalar(float f) {
    union { float f; u32 i; } x; x.f = f;
    u32 u = x.i + 0x7FFFu + ((x.i >> 16) & 1u);
    return (u16)(u >> 16);
}

// packed f32x2 -> bf16x2 (RNE). gfx950 has v_cvt_pk_bf16_f32.
__device__ __forceinline__ u32 cvt2(float a, float b) {
#if __has_builtin(__builtin_amdgcn_cvt_pk_bf16_f32)
    auto p = __builtin_amdgcn_cvt_pk_bf16_f32(a, b);
    u32 w; __builtin_memcpy(&w, &p, sizeof(u32));
    return w;
#else
    return (u32)f2bf_scalar(a) | ((u32)f2bf_scalar(b) << 16);
#endif
}
__device__ __forceinline__ u16 cvt1(float a) { return (u16)cvt2(a, a); }

// lrelu = max(x, 0.2x): 2 VALU ops, exact for all x
__device__ __forceinline__ float lrelu(float x) { return fmaxf(x, NSLOPE * x); }

__device__ __forceinline__ float fexp2(float x) {
#if __has_builtin(__builtin_amdgcn_exp2f)
    return __builtin_amdgcn_exp2f(x);   // v_exp_f32 = 2^x
#else
    return exp2f(x);
#endif
}

__device__ __forceinline__ float frcp(float x) {
#if __has_builtin(__builtin_amdgcn_rcpf)
    return __builtin_amdgcn_rcpf(x);    // v_rcp_f32, ~1ulp — fine at this tolerance
#else
    return 1.f / x;
#endif
}

__device__ __forceinline__ float ldf(const void* p, size_t i) { return ((const f32a*)p)[i]; }

// B-fragment for mfma_f32_16x16x32_bf16 from fp32 global W, BN scale folded in:
// lane holds B[k = ks*32 + q*8 + j][n = nt*16 + t] * scale   (epilogue only)
__device__ __forceinline__ short8 load_bfrag(const void* W, int K, int Cn, int ks, int nt,
                                             int q, int t, float scale) {
    U8 x;
#pragma unroll
    for (int j = 0; j < 8; ++j) {
        int k = ks * 32 + q * 8 + j;
        x.u[j] = (k < K) ? f2bf_scalar(ldf(W, (size_t)k * Cn + nt * 16 + t) * scale) : (u16)0;
    }
    return x.s;
}

// A-fragment from per-wave LDS tile row-major [16][68] bf16 — two b64 reads
// (byte addr row*136 + ks*64 + q*16: 8B-aligned). Same-wave DS is in-order.
__device__ __forceinline__ short8 lds_afrag(const u16* buf, int row, int ks, int q) {
    const u16* cp = buf + row * 68 + ks * 32 + q * 8;
    u32x2a a = *(const u32x2a*)cp;
    u32x2a b = *(const u32x2a*)(cp + 4);
    U8 x; x.w[0] = a.x; x.w[1] = a.y; x.w[2] = b.x; x.w[3] = b.y;
    return x.s;
}

// B-fragment from a per-lane weight base (s_w*T + t*64 + swizzled slot for this ks,q):
// one ds_read_b128 at imm offset nt*2048B. XOR slot swizzle keeps a q-group's 16
// lanes spread over all 8 16B slots (2 lanes/bank at the b128 floor = free).
__device__ __forceinline__ short8 lds_wfrag2(const u16* base, int nt) {
    return *(const short8a*)(base + (nt << 10));
}

#define MFMA(a, b, c) __builtin_amdgcn_mfma_f32_16x16x32_bf16((a), (b), (c), 0, 0, 0)

// One wave = 2 groups of 16 points, processed sequentially. Tiles are PER-WAVE: no
// in-loop barriers.
// R15 (on R8's 8-wave base): R8's grid 1024 = 4 blocks/CU work with only 3 LDS-resident
// -> low-occupancy tail (avg 48%); and (6,6)'s ~85-reg budget spilled 3 dwords/thread
// (WRITE 39 vs 32.8 MB). Fix both with grid 512 x 2 groups/wave: exactly 2 blocks/CU,
// both resident (104KB LDS), zero tail; waves_per_eu(4,4) restores the 128-reg budget
// (R7 proved the body fits with ~44 regs headroom) -> zero spill. Weight prologue
// amortizes over 2x work. All R7/R8 structure unchanged: de-masked load_raw (wraw rows
// k=11..31 exact zeros), unroll 2, f32 hv, epilogue fused per-nt, anti-LICM 'licm',
// slot-permuted packed LDS writes, select-then-rcp softmax, bias-in-row-10.
__global__
__attribute__((amdgpu_flat_work_group_size(512, 512), amdgpu_waves_per_eu(4, 4)))
void lfa_kernel(
    const void* __restrict__ feat,        // (131072, 32) fp32
    const void* __restrict__ rawf,        // (131072*16, 10) fp32
    const int*  __restrict__ nbidx,       // (131072, 16) int32
    const void* __restrict__ w_raw,
    const void* __restrict__ b_raw, const void* __restrict__ g_raw,
    const void* __restrict__ be_raw, const void* __restrict__ m_raw,
    const void* __restrict__ v_raw,
    const void* __restrict__ w_nb,
    const void* __restrict__ b_nb, const void* __restrict__ g_nb,
    const void* __restrict__ be_nb, const void* __restrict__ m_nb,
    const void* __restrict__ v_nb,
    const void* __restrict__ w_attn,
    const void* __restrict__ w_out,
    const void* __restrict__ b_out, const void* __restrict__ g_out,
    const void* __restrict__ be_out, const void* __restrict__ m_out,
    const void* __restrict__ v_out,
    const void* __restrict__ w_sc,
    const void* __restrict__ b_sc, const void* __restrict__ g_sc,
    const void* __restrict__ be_sc, const void* __restrict__ m_sc,
    const void* __restrict__ v_sc,
    float* __restrict__ outp)             // (131072, 64) fp32
{
    // h tile aliases the cat tile: every iteration fully rewrites cat[0..15][0..63]
    // before phase B reads it, and same-wave DS ops execute in order.
    //
    // K-slot <-> channel permutation (so MFMA outputs pack into contiguous LDS slots):
    //   cat slots  0..31 : gather channel s (identity)
    //   cat slots 32..63 : raw-MLP channel ((s-32)&1)*16 + ((s-32)>>1)   [slot 32+2t+nt]
    //   h   slots  0..63 : h channel (s&3)*16 + (s>>2)                   [slot 4t+nt]
    // s_wnbT rows use the cat permutation; s_wattT rows use the h permutation.
    __shared__ __align__(16) u16 s_cat[8][16 * 68];
    __shared__ __align__(16) u16 s_pool[8][16 * 68];
    __shared__ __align__(16) u16 s_wnbT[64 * 64];    // W_nb^T * s_nb, bf16, swizzled
    __shared__ __align__(16) u16 s_wattT[64 * 64];   // W_attn^T * log2e, bf16, swizzled
    __shared__ float2 s_pr_raw[32];
    __shared__ float2 s_pr_nb[64];
    __shared__ float2 s_pr_out[64];
    __shared__ float2 s_pr_sc[64];

    const int tid  = threadIdx.x;
    const int lane = tid & 63;
    const int wv   = __builtin_amdgcn_readfirstlane(tid >> 6);   // wave-uniform by construction
    const int t    = lane & 15;
    const int q    = lane >> 4;

    // ---- fold BN (+linear bias) into per-channel scale/bias ----
    if (tid < 64) {
        int c = tid;
        float s = ldf(g_nb, c) * rsqrtf(ldf(v_nb, c) + BNEPS);
        s_pr_nb[c] = make_float2(s, (ldf(b_nb, c) - ldf(m_nb, c)) * s + ldf(be_nb, c));
    } else if (tid < 128) {
        int c = tid - 64;
        float s = ldf(g_out, c) * rsqrtf(ldf(v_out, c) + BNEPS);
        s_pr_out[c] = make_float2(s, (ldf(b_out, c) - ldf(m_out, c)) * s + ldf(be_out, c));
    } else if (tid < 192) {
        int c = tid - 128;
        float s = ldf(g_sc, c) * rsqrtf(ldf(v_sc, c) + BNEPS);
        s_pr_sc[c] = make_float2(s, (ldf(b_sc, c) - ldf(m_sc, c)) * s + ldf(be_sc, c));
    } else if (tid < 224) {
        int c = tid - 192;
        float s = ldf(g_raw, c) * rsqrtf(ldf(v_raw, c) + BNEPS);
        s_pr_raw[c] = make_float2(s, (ldf(b_raw, c) - ldf(m_raw, c)) * s + ldf(be_raw, c));
    }
    __syncthreads();

    // ---- cooperative fill of the shared bf16 weight images (coalesced: n fast) ----
#pragma unroll 4
    for (int idx = tid; idx < 64 * 64; idx += 512) {
        int n = idx & 63, s = idx >> 6;    // s = K-slot
        int off = (n << 6) | (((s >> 3) ^ (n & 7)) << 3) | (s & 7);
        int knb = (s < 32) ? s : 32 + (((s - 32) & 1) << 4) + ((s - 32) >> 1);
        int kat = ((s & 3) << 4) + (s >> 2);
        s_wnbT[off]  = f2bf_scalar(ldf(w_nb,   (size_t)knb * 64 + n) * s_pr_nb[n].x);
        s_wattT[off] = f2bf_scalar(ldf(w_attn, (size_t)kat * 64 + n) * LOG2E);
    }
    __syncthreads();   // last block-wide barrier

    // ---- small loop-resident state: raw weights (scale folded; BN bias in row 10) ----
    short8 wraw[2];
    float bias_nb[4];
#pragma unroll
    for (int nt = 0; nt < 2; ++nt) {
        int c = nt * 16 + t;
        float2 pr = s_pr_raw[c];
        U8 x;
#pragma unroll
        for (int j = 0; j < 8; ++j) {
            int k = q * 8 + j;
            float v = (k < 10) ? ldf(w_raw, (size_t)k * 32 + c) * pr.x
                               : (k == 10 ? pr.y : 0.f);
            x.u[j] = f2bf_scalar(v);
        }
        wraw[nt] = x.s;
    }
#pragma unroll
    for (int nt = 0; nt < 4; ++nt) bias_nb[nt] = s_pr_nb[nt * 16 + t].y;

    // per-lane swizzled weight bases (iter-invariant; frag read = base + nt*2048B imm)
    const u16* wnb_base[2];
    const u16* watt_base[2];
#pragma unroll
    for (int ks = 0; ks < 2; ++ks) {
        int lane_off = (t << 6) + ((((ks << 2) | q) ^ (t & 7)) << 3);
        wnb_base[ks]  = s_wnbT  + lane_off;
        watt_base[ks] = s_wattT + lane_off;
    }

    u16* catw  = &s_cat[wv][0];
    u16* poolw = &s_pool[wv][0];

    const f32x4 zf = {0.f, 0.f, 0.f, 0.f};
    const int m_ = lane >> 2;               // gather: neighbor index this lane handles
    const int pc = lane & 3;                // gather: 8-float piece
    const float* fpb = (const float*)feat;
    const bool q_eq1 = (q == 1);
    const int gbase = (blockIdx.x * 8 + wv) * 2;   // 8192 groups, grid 512 x 8 waves x 2

    int licm = 0;   // always 0; opaque to the compiler (anti-LICM for weight reads)

#pragma unroll 1
    for (int gg = 0; gg < 2; ++gg) {
        const int g  = gbase + gg;
        const int P0 = g * 16;
        const int bb = P0 >> 16;            // group never straddles batch boundary
        const size_t fb = (size_t)bb << 16;

        // per-group base pointers
        const int*  nbp  = nbidx + P0 * 16 + m_;                      // idx: nbp[p*16]
        const f32a* rawp = (const f32a*)rawf + (size_t)P0 * 160 + (size_t)t * 10;

        // branch-free loaders -> SSA f32x4 pairs (no structs: avoid stack demotion)
        auto load_gather = [&](int ix, f32x4& a, f32x4& b) {
            const float* fp = fpb + (fb + (size_t)ix) * 32 + pc * 8;
            a = *(const f32x4a*)fp;
            b = *(const f32x4a*)(fp + 4);
        };
        // lane(t,q) supplies raw[t][k], k=q*8+j; rows are 10 floats. q0 reads f0..7;
        // q1 reads f8..9 (b64 at +8) and injects bias-carrier 1.0 at k=10. All OTHER
        // slots (q1 k=11..15, all of q2/q3) multiply EXACT-ZERO wraw rows in the
        // MFMA, so they may hold finite garbage — no masking needed (0 x finite = 0).
        auto load_raw = [&](int p, f32x4& a, f32x4& b) {
            const f32a* rp = rawp + (size_t)p * 160;
            f32x2a L0 = *(const f32x2a*)(rp + ((q & 1) << 3));  // q0:f01  q1:f89
            f32x2a L1 = *(const f32x2a*)(rp + 2);
            f32x2a L2 = *(const f32x2a*)(rp + 4);
            f32x2a L3 = *(const f32x2a*)(rp + 6);
            a.x = L0.x;
            a.y = L0.y;
            a.z = q_eq1 ? 1.f : L1.x;       // k=10 bias carrier for q1
            a.w = L1.y;
            b.x = L2.x; b.y = L2.y;
            b.z = L3.x; b.w = L3.y;
        };

        // ---- software-pipeline preamble: loop-carried state is PACKED bf16 (8 u32) ----
        u32x2_t gpa, gpb;       // gather row, bf16x2 packed (lo 4, hi 4)
        u32 rp0, rp1, rp2, rp3; // raw-MLP A fragment, packed
        {
            int ixA = nbp[0];
            f32x4 g0, g1, r0, r1;
            load_gather(ixA, g0, g1);
            load_raw(0, r0, r1);
            gpa.x = cvt2(g0.x, g0.y); gpa.y = cvt2(g0.z, g0.w);
            gpb.x = cvt2(g1.x, g1.y); gpb.y = cvt2(g1.z, g1.w);
            rp0 = cvt2(r0.x, r0.y); rp1 = cvt2(r0.z, r0.w);
            rp2 = cvt2(r1.x, r1.y); rp3 = cvt2(r1.z, r1.w);
        }
        int ixB = nbp[16];

#pragma unroll 2
        for (int p = 0; p < 16; ++p) {
            asm volatile("" : "+v"(licm));

            // next-next neighbor index (1 reg, cheap; full-body latency cover)
            const int pnn = (p + 2 < 16) ? p + 2 : 15;
            int ixC = nbp[pnn * 16];

            // ---- phase A: gather -> cat[m][0..31] (carried packed, b64 writes) ----
            *(u32x2a*)(catw + m_ * 68 + pc * 8)     = gpa;
            *(u32x2a*)(catw + m_ * 68 + pc * 8 + 4) = gpb;

            // ---- raw MLP via MFMA (bias in row 10) -> cat slots 32+2t+nt (b32) ----
            {
                U8 au;
                au.w[0] = rp0; au.w[1] = rp1; au.w[2] = rp2; au.w[3] = rp3;
                short8 ar = au.s;
                f32x4 racc0 = MFMA(ar, wraw[0], zf);
                f32x4 racc1 = MFMA(ar, wraw[1], zf);
#pragma unroll
                for (int r = 0; r < 4; ++r) {
                    u32 wpk = cvt2(lrelu(racc0[r]), lrelu(racc1[r]));
                    *(u32a*)(catw + (q * 4 + r) * 68 + 32 + 2 * t) = wpk;
                }
            }

            // ---- MID-BODY prefetch issue: carried regs dead; loads cover B+C ----
            const int pn = (p + 1 < 16) ? p + 1 : 15;
            f32x4 gb0, gb1, rb0, rb1;
            load_gather(ixB, gb0, gb1);
            load_raw(pn, rb0, rb1);

            // ---- phase B: h = lrelu(cat @ (w_nb*s) + bias); hv stays f32 ----
            short8 a0 = lds_afrag(catw, t, 0, q);
            short8 a1 = lds_afrag(catw, t, 1, q);
            const u16* wb0 = wnb_base[0] + licm;
            const u16* wb1 = wnb_base[1] + licm;
            float hv[4][4];
            {
                f32x4 c0 = MFMA(a0, lds_wfrag2(wb0, 0), zf);
                c0 = MFMA(a1, lds_wfrag2(wb1, 0), c0);
                f32x4 c1 = MFMA(a0, lds_wfrag2(wb0, 1), zf);
                c1 = MFMA(a1, lds_wfrag2(wb1, 1), c1);
                f32x4 c2 = MFMA(a0, lds_wfrag2(wb0, 2), zf);
                c2 = MFMA(a1, lds_wfrag2(wb1, 2), c2);
                f32x4 c3 = MFMA(a0, lds_wfrag2(wb0, 3), zf);
                c3 = MFMA(a1, lds_wfrag2(wb1, 3), c3);
#pragma unroll
                for (int r = 0; r < 4; ++r) {
                    hv[0][r] = lrelu(c0[r] + bias_nb[0]);
                    hv[1][r] = lrelu(c1[r] + bias_nb[1]);
                    hv[2][r] = lrelu(c2[r] + bias_nb[2]);
                    hv[3][r] = lrelu(c3[r] + bias_nb[3]);
                }
            }
#pragma unroll
            for (int r = 0; r < 4; ++r) {
                u32x2_t w2;
                w2.x = cvt2(hv[0][r], hv[1][r]);
                w2.y = cvt2(hv[2][r], hv[3][r]);
                *(u32x2a*)(catw + (q * 4 + r) * 68 + 4 * t) = w2;   // h slot 4t+nt
            }

            // ---- phase C: scores = h @ (w_attn*log2e); softmax over m; pool ----
            short8 h0 = lds_afrag(catw, t, 0, q);
            short8 h1 = lds_afrag(catw, t, 1, q);
            const u16* wa0 = watt_base[0] + licm;
            const u16* wa1 = watt_base[1] + licm;
            float pvn = 0.f, pvd = 1.f;
#pragma unroll
            for (int nt = 0; nt < 4; ++nt) {
                f32x4 s = MFMA(h0, lds_wfrag2(wa0, nt), zf);
                s = MFMA(h1, lds_wfrag2(wa1, nt), s);
                float num = 0.f, den = 0.f;
#pragma unroll
                for (int r = 0; r < 4; ++r) {
                    float e = fexp2(s[r]);  // no max-sub: |score*log2e| << 126
                    num = fmaf(e, hv[nt][r], num);
                    den += e;
                }
                num += __shfl_xor(num, 16); den += __shfl_xor(den, 16);
                num += __shfl_xor(num, 32); den += __shfl_xor(den, 32);
                // lane only consumes its own q's channel group: select, divide once
                bool sel = (q == nt);
                pvn = sel ? num : pvn;
                pvd = sel ? den : pvd;
            }
            poolw[p * 68 + q * 16 + t] = cvt1(pvn * frcp(pvd));

            // ---- bottom: convert this iteration's prefetch into the packed carry ----
            gpa.x = cvt2(gb0.x, gb0.y); gpa.y = cvt2(gb0.z, gb0.w);
            gpb.x = cvt2(gb1.x, gb1.y); gpb.y = cvt2(gb1.z, gb1.w);
            rp0 = cvt2(rb0.x, rb0.y); rp1 = cvt2(rb0.z, rb0.w);
            rp2 = cvt2(rb1.x, rb1.y); rp3 = cvt2(rb1.z, rb1.w);
            ixB = ixC;
        }

        // ---- epilogue, fused per-nt (peak ~70 regs; R6 fix — full-resident frags
        //      were the spill driver at every 128-reg budget) ----
        short8 pf0 = lds_afrag(poolw, t, 0, q);
        short8 pf1 = lds_afrag(poolw, t, 1, q);
        U8 sxu;
        {
            const float* fp = fpb + (size_t)(P0 + t) * 32 + q * 8;
            f32x4a v0 = *(const f32x4a*)fp;
            f32x4a v1 = *(const f32x4a*)(fp + 4);
            sxu.w[0] = cvt2(v0.x, v0.y); sxu.w[1] = cvt2(v0.z, v0.w);
            sxu.w[2] = cvt2(v1.x, v1.y); sxu.w[3] = cvt2(v1.z, v1.w);
        }
        short8 scf = sxu.s;
#pragma unroll 1
        for (int nt = 0; nt < 4; ++nt) {
            float2 po = s_pr_out[nt * 16 + t];
            float2 ps = s_pr_sc[nt * 16 + t];
            short8 wo0 = load_bfrag(w_out, 64, 64, 0, nt, q, t, po.x);
            short8 wo1 = load_bfrag(w_out, 64, 64, 1, nt, q, t, po.x);
            short8 ws  = load_bfrag(w_sc, 32, 64, 0, nt, q, t, ps.x);
            float bos = po.y + ps.y;
            f32x4 oa = {bos, bos, bos, bos};
            oa = MFMA(pf0, wo0, oa);
            oa = MFMA(pf1, wo1, oa);
            f32x4 sa = MFMA(scf, ws, zf);
#pragma unroll
            for (int r = 0; r < 4; ++r)
                outp[(size_t)(P0 + q * 4 + r) * 64 + nt * 16 + t] = lrelu(oa[r] + sa[r]);
        }
    }
}

extern "C" void kernel_launch(void* const* d_in, const int* in_sizes, int n_in,
                              void* d_out, int out_size, void* d_ws, size_t ws_size,
                              hipStream_t stream) {
    hipLaunchKernelGGL(lfa_kernel, dim3(512), dim3(512), 0, stream,
                       d_in[0], d_in[1], (const int*)d_in[2],
                       d_in[3], d_in[4], d_in[5], d_in[6], d_in[7], d_in[8],
                       d_in[9], d_in[10], d_in[11], d_in[12], d_in[13], d_in[14],
                       d_in[15],
                       d_in[16], d_in[17], d_in[18], d_in[19], d_in[20], d_in[21],
                       d_in[22], d_in[23], d_in[24], d_in[25], d_in[26], d_in[27],
                       (float*)d_out);
}